// Round 3
// baseline (29254.123 us; speedup 1.0000x reference)
//
#include <hip/hip_runtime.h>
#include <cstddef>
#include <cstdint>

// DA-RNN for MI355X — round 3 (resubmit of R2: broker timeout, fix untested).
// B=2048, T=32, I=512, H=D=E=1024, 4H=4096.
//
// Identity: encoder input-attention softmax(base[:,None]+xw) == softmax(xw)
// (base is a per-row scalar; softmax is shift-invariant) -> alpha is
// step-independent; enc_attn_b / w_h / w_s are mathematically dead.
//
// R1 crashed (GPU abort, no counters). Theory: workspace overflow — old
// layout needed 738 MiB of d_ws, ws_size never checked. This version:
//   * X_tilde never materialized: encoder GEMM scales A by alpha on load
//     (saves 134 MiB + traffic)
//   * if ws_size >= ~610 MiB: all-fp32 path
//     else: Xenc/Xproj stored as raw bf16 (ushort) -> ~324 MiB total
// Branch depends only on ws_size (constant), so every call does identical
// work (graph-capture safe).

#define B_ 2048
#define T_ 32
#define I_ 512
#define H_ 1024
#define G_ 4096  // 4*H
#define E_ 1024

// ---- bf16 helpers (raw ushort storage; bf16 = top 16 bits of f32) ----------
__device__ __forceinline__ float bf2f(unsigned short u) {
    union { float f; unsigned v; } w; w.v = ((unsigned)u) << 16; return w.f;
}
__device__ __forceinline__ unsigned short f2bf(float f) {
    union { float f; unsigned v; } w; w.f = f;
    unsigned r = w.v + 0x7fff + ((w.v >> 16) & 1);  // round-to-nearest-even
    return (unsigned short)(r >> 16);
}
template <typename T>
__device__ __forceinline__ float ld1(const T* p) {
    if constexpr (sizeof(T) == 4) return *(const float*)p;
    else return bf2f(*(const unsigned short*)p);
}
template <typename T>
__device__ __forceinline__ float4 ld4(const T* p) {
    if constexpr (sizeof(T) == 4) {
        return *(const float4*)p;
    } else {
        const ushort4 u = *(const ushort4*)p;
        float4 r; r.x = bf2f(u.x); r.y = bf2f(u.y); r.z = bf2f(u.z); r.w = bf2f(u.w);
        return r;
    }
}

// ---------------------------------------------------------------------------
// Generic GEMM:  C[m,n] = sum_k s1[m,k]*A1[m,k]*B1[n,k] + sum_k A2[m,k]*B2[n,k]
//                          + bias1[n] + bias2[n] + u[m]*v[n]
// A row-major (M x K, ld), B row-major (N x K, ld)  => computes A @ B^T.
// TA: element type of A1/A2 (float or raw-bf16 ushort). TC: store type of C.
// ascale (optional, fp32, ld=ldsc) multiplies A1 element-wise.
// ---------------------------------------------------------------------------
template <int BM, int BN, int BK, int TM, int TN, typename TA, typename TC>
__global__ __launch_bounds__(256) void gemm(
    int M, int N,
    const TA* __restrict__ A1, int lda1, const float* __restrict__ B1, int ldb1, int K1,
    const TA* __restrict__ A2, int lda2, const float* __restrict__ B2, int ldb2, int K2,
    const float* __restrict__ ascale, int ldsc,
    const float* __restrict__ bias1, const float* __restrict__ bias2,
    const float* __restrict__ u, const float* __restrict__ v,
    TC* __restrict__ C, int ldc)
{
    constexpr int TCOLS = BN / TN;
    constexpr int TROWS = BM / TM;
    static_assert(TCOLS * TROWS == 256, "bad tiling");
    constexpr int KCH = BK / 4;              // float4 chunks along k
    constexpr int ROWS_PER_PASS = 256 / KCH;

    __shared__ float As[BK][BM + 4];
    __shared__ float Bs[BK][BN + 4];

    const int tid = threadIdx.x;
    const int tn = tid % TCOLS;
    const int tm = tid / TCOLS;
    const int bn = blockIdx.x * BN;
    const int bm = blockIdx.y * BM;

    const int lrow = tid / KCH;
    const int lkc  = (tid % KCH) * 4;

    float acc[TM][TN];
#pragma unroll
    for (int i = 0; i < TM; ++i)
#pragma unroll
        for (int j = 0; j < TN; ++j) acc[i][j] = 0.0f;

    for (int pair = 0; pair < 2; ++pair) {
        const TA* A  = pair ? A2 : A1;
        const float* Bp = pair ? B2 : B1;
        const float* sc = pair ? nullptr : ascale;
        const int lda = pair ? lda2 : lda1;
        const int ldb = pair ? ldb2 : ldb1;
        const int K   = pair ? K2 : K1;
        if (K == 0) continue;
        for (int k0 = 0; k0 < K; k0 += BK) {
            __syncthreads();
#pragma unroll
            for (int r = 0; r < BM; r += ROWS_PER_PASS) {
                const int row = bm + r + lrow;
                float4 val = ld4(A + (size_t)row * lda + (k0 + lkc));
                if (sc) {
                    const float4 s = *(const float4*)(sc + (size_t)row * ldsc + (k0 + lkc));
                    val.x *= s.x; val.y *= s.y; val.z *= s.z; val.w *= s.w;
                }
                As[lkc + 0][r + lrow] = val.x;
                As[lkc + 1][r + lrow] = val.y;
                As[lkc + 2][r + lrow] = val.z;
                As[lkc + 3][r + lrow] = val.w;
            }
#pragma unroll
            for (int r = 0; r < BN; r += ROWS_PER_PASS) {
                const float4 val = *(const float4*)(Bp + (size_t)(bn + r + lrow) * ldb + (k0 + lkc));
                Bs[lkc + 0][r + lrow] = val.x;
                Bs[lkc + 1][r + lrow] = val.y;
                Bs[lkc + 2][r + lrow] = val.z;
                Bs[lkc + 3][r + lrow] = val.w;
            }
            __syncthreads();
#pragma unroll
            for (int k = 0; k < BK; ++k) {
                float a[TM], bv[TN];
#pragma unroll
                for (int i = 0; i < TM; ++i) a[i] = As[k][tm * TM + i];
#pragma unroll
                for (int j = 0; j < TN; ++j) bv[j] = Bs[k][tn * TN + j];
#pragma unroll
                for (int i = 0; i < TM; ++i)
#pragma unroll
                    for (int j = 0; j < TN; ++j)
                        acc[i][j] = fmaf(a[i], bv[j], acc[i][j]);
            }
        }
    }

#pragma unroll
    for (int i = 0; i < TM; ++i) {
        const int m = bm + tm * TM + i;
        const float um = u ? u[m] : 0.0f;
#pragma unroll
        for (int j = 0; j < TN; j += 4) {
            const int n = bn + tn * TN + j;
            float r[4];
#pragma unroll
            for (int q = 0; q < 4; ++q) {
                float val = acc[i][j + q];
                if (bias1) val += bias1[n + q];
                if (bias2) val += bias2[n + q];
                if (u)     val += um * v[n + q];
                r[q] = val;
            }
            if constexpr (sizeof(TC) == 4) {
                float4 f; f.x = r[0]; f.y = r[1]; f.z = r[2]; f.w = r[3];
                *(float4*)((float*)C + (size_t)m * ldc + n) = f;
            } else {
                ushort4 s;
                s.x = f2bf(r[0]); s.y = f2bf(r[1]); s.z = f2bf(r[2]); s.w = f2bf(r[3]);
                *(ushort4*)((unsigned short*)C + (size_t)m * ldc + n) = s;
            }
        }
    }
}

// ---------------------------------------------------------------------------
// Encoder input attention: xw[b,i]=sum_t X[b,t,i]*w_x[t]; alpha=softmax_i(xw)
// ---------------------------------------------------------------------------
__global__ __launch_bounds__(256) void attn_prep(
    const float* __restrict__ X, const float* __restrict__ eaw, float* __restrict__ alpha)
{
    const int b = blockIdx.x, tid = threadIdx.x;
    __shared__ float wx[T_];
    __shared__ float red[4];
    if (tid < T_) wx[tid] = eaw[2 * H_ + tid];
    __syncthreads();
    const float* xb = X + (size_t)b * T_ * I_;
    float a0 = 0.0f, a1 = 0.0f;
#pragma unroll
    for (int t = 0; t < T_; ++t) {
        a0 = fmaf(xb[t * I_ + tid], wx[t], a0);
        a1 = fmaf(xb[t * I_ + tid + 256], wx[t], a1);
    }
    float m = fmaxf(a0, a1);
#pragma unroll
    for (int off = 32; off; off >>= 1) m = fmaxf(m, __shfl_down(m, off));
    if ((tid & 63) == 0) red[tid >> 6] = m;
    __syncthreads();
    m = fmaxf(fmaxf(red[0], red[1]), fmaxf(red[2], red[3]));
    __syncthreads();
    const float e0 = expf(a0 - m), e1 = expf(a1 - m);
    float ssum = e0 + e1;
#pragma unroll
    for (int off = 32; off; off >>= 1) ssum += __shfl_down(ssum, off);
    if ((tid & 63) == 0) red[tid >> 6] = ssum;
    __syncthreads();
    const float inv = 1.0f / (red[0] + red[1] + red[2] + red[3]);
    alpha[(size_t)b * I_ + tid]       = e0 * inv;
    alpha[(size_t)b * I_ + tid + 256] = e1 * inv;
}

// ---------------------------------------------------------------------------
// LSTM pointwise; optionally writes h into Xenc[b,t,:] (type TX).
// ---------------------------------------------------------------------------
template <typename TX>
__global__ __launch_bounds__(256) void lstm_pw(
    const float* __restrict__ gates, float* __restrict__ h, float* __restrict__ c,
    TX* __restrict__ xenc, int t)
{
    const size_t idx = (size_t)blockIdx.x * 256 + threadIdx.x;  // < B*H
    const int b = (int)(idx >> 10);
    const int j = (int)(idx & 1023);
    const float* g = gates + ((size_t)b << 12);
    const float gi = g[j], gf = g[j + 1024], gg = g[j + 2048], go = g[j + 3072];
    const float si = 1.0f / (1.0f + expf(-gi));
    const float sf = 1.0f / (1.0f + expf(-gf));
    const float so = 1.0f / (1.0f + expf(-go));
    const float cn = sf * c[idx] + si * tanhf(gg);
    const float hn = so * tanhf(cn);
    c[idx] = cn;
    h[idx] = hn;
    if (xenc) {
        if constexpr (sizeof(TX) == 4) xenc[(((size_t)b * T_ + t) << 10) + j] = hn;
        else ((unsigned short*)xenc)[(((size_t)b * T_ + t) << 10) + j] = f2bf(hn);
    }
}

// ---------------------------------------------------------------------------
// Fused decoder attention step: scores -> softmax -> context -> y_tilde.
// One block per batch row; thread owns e = tid + 256*q, q<4.
// ---------------------------------------------------------------------------
template <typename TX>
__global__ __launch_bounds__(256) void dec_attn(
    const float* __restrict__ pre, const TX* __restrict__ Xproj,
    const TX* __restrict__ Xenc, const float* __restrict__ W2,
    const float* __restrict__ b2, const float* __restrict__ fc_w,
    const float* __restrict__ fc_b, const float* __restrict__ y_prev,
    int step, float* __restrict__ ctx, float* __restrict__ ytil)
{
    const int b = blockIdx.x, tid = threadIdx.x;
    __shared__ float red[4];
    __shared__ float sc[T_];
    float pr[4], w2r[4];
#pragma unroll
    for (int q = 0; q < 4; ++q) {
        pr[q]  = pre[(size_t)b * 1024 + tid + 256 * q];
        w2r[q] = W2[tid + 256 * q];
    }
    const TX* xp = Xproj + (size_t)b * T_ * 1024;
    for (int t = 0; t < T_; ++t) {
        float s = 0.0f;
#pragma unroll
        for (int q = 0; q < 4; ++q)
            s += tanhf(pr[q] + ld1(xp + t * 1024 + tid + 256 * q)) * w2r[q];
#pragma unroll
        for (int off = 32; off; off >>= 1) s += __shfl_down(s, off);
        if ((tid & 63) == 0) red[tid >> 6] = s;
        __syncthreads();
        if (tid == 0) sc[t] = red[0] + red[1] + red[2] + red[3] + b2[0];
        __syncthreads();
    }
    float mx = -1e30f;
#pragma unroll
    for (int t = 0; t < T_; ++t) mx = fmaxf(mx, sc[t]);
    float beta[T_];
    float ssum = 0.0f;
#pragma unroll
    for (int t = 0; t < T_; ++t) { beta[t] = expf(sc[t] - mx); ssum += beta[t]; }
    const float inv = 1.0f / ssum;
    const TX* xe = Xenc + (size_t)b * T_ * 1024;
    float cx[4] = {0.0f, 0.0f, 0.0f, 0.0f};
    for (int t = 0; t < T_; ++t) {
        const float bt = beta[t];
#pragma unroll
        for (int q = 0; q < 4; ++q)
            cx[q] = fmaf(bt, ld1(xe + t * 1024 + tid + 256 * q), cx[q]);
    }
    float yt = 0.0f;
#pragma unroll
    for (int q = 0; q < 4; ++q) {
        const float cv = cx[q] * inv;
        ctx[(size_t)b * 1024 + tid + 256 * q] = cv;
        yt += cv * fc_w[tid + 256 * q];
    }
#pragma unroll
    for (int off = 32; off; off >>= 1) yt += __shfl_down(yt, off);
    if ((tid & 63) == 0) red[tid >> 6] = yt;
    __syncthreads();
    if (tid == 0)
        ytil[b] = red[0] + red[1] + red[2] + red[3]
                + y_prev[(size_t)b * T_ + step] * fc_w[1024] + fc_b[0];
}

// ---------------------------------------------------------------------------
__global__ __launch_bounds__(256) void final_out(
    const float* __restrict__ d, const float* __restrict__ ctx,
    const float* __restrict__ ffw, const float* __restrict__ ffb,
    float* __restrict__ out)
{
    const int b = blockIdx.x, tid = threadIdx.x;
    float s = 0.0f;
#pragma unroll
    for (int q = 0; q < 4; ++q) {
        const int e = tid + 256 * q;
        s += d[(size_t)b * 1024 + e] * ffw[e] + ctx[(size_t)b * 1024 + e] * ffw[1024 + e];
    }
#pragma unroll
    for (int off = 32; off; off >>= 1) s += __shfl_down(s, off);
    __shared__ float red[4];
    if ((tid & 63) == 0) red[tid >> 6] = s;
    __syncthreads();
    if (tid == 0) out[b] = red[0] + red[1] + red[2] + red[3] + ffb[0];
}

// ---------------------------------------------------------------------------
template <typename TX>
static void run_pipeline(void* const* d_in, float* out, char* ws, hipStream_t stream)
{
    const float* X      = (const float*)d_in[0];
    const float* y_prev = (const float*)d_in[1];
    const float* eaw    = (const float*)d_in[2];
    const float* Wih_e  = (const float*)d_in[4];
    const float* Whh_e  = (const float*)d_in[5];
    const float* bih_e  = (const float*)d_in[6];
    const float* bhh_e  = (const float*)d_in[7];
    const float* W1     = (const float*)d_in[8];
    const float* b1     = (const float*)d_in[9];
    const float* W2     = (const float*)d_in[10];
    const float* b2     = (const float*)d_in[11];
    const float* Wih_d  = (const float*)d_in[12];
    const float* Whh_d  = (const float*)d_in[13];
    const float* bih_d  = (const float*)d_in[14];
    const float* bhh_d  = (const float*)d_in[15];
    const float* fc_w   = (const float*)d_in[16];
    const float* fc_b   = (const float*)d_in[17];
    const float* ff_w   = (const float*)d_in[18];
    const float* ff_b   = (const float*)d_in[19];

    auto au = [](size_t x) { return (x + 255) & ~(size_t)255; };
    char* p = ws;
    float* alpha = (float*)p;  p += au((size_t)B_ * I_ * 4);
    TX*    Xenc  = (TX*)p;     p += au((size_t)B_ * T_ * H_ * sizeof(TX));
    TX*    Xproj = (TX*)p;     p += au((size_t)B_ * T_ * H_ * sizeof(TX));
    float* gates = (float*)p;  p += au((size_t)B_ * G_ * 4);
    float* h     = (float*)p;  p += au((size_t)B_ * H_ * 4);
    float* c     = (float*)p;  p += au((size_t)B_ * H_ * 4);
    float* pre   = (float*)p;  p += au((size_t)B_ * E_ * 4);
    float* ctx   = (float*)p;  p += au((size_t)B_ * E_ * 4);
    float* ytil  = (float*)p;

    hipMemsetAsync(h, 0, (size_t)B_ * H_ * sizeof(float), stream);
    hipMemsetAsync(c, 0, (size_t)B_ * H_ * sizeof(float), stream);

    attn_prep<<<B_, 256, 0, stream>>>(X, eaw, alpha);

    // ---- encoder: gates = (alpha*X_t) @ Wih_e^T + h @ Whh_e^T + biases
    for (int t = 0; t < T_; ++t) {
        gemm<128, 128, 16, 8, 8, float, float><<<dim3(G_ / 128, B_ / 128), 256, 0, stream>>>(
            B_, G_,
            X + (size_t)t * I_, T_ * I_, Wih_e, I_, I_,
            h, H_, Whh_e, H_, H_,
            alpha, I_,
            bih_e, bhh_e, nullptr, nullptr, gates, G_);
        lstm_pw<TX><<<(B_ * H_) / 256, 256, 0, stream>>>(gates, h, c, Xenc, t);
    }

    // ---- Xenc_proj = Xenc @ W1_x^T + b1   (W1_x = W1[:, 2048:], ld 3072)
    gemm<128, 128, 16, 8, 8, TX, TX><<<dim3(E_ / 128, (B_ * T_) / 128), 256, 0, stream>>>(
        B_ * T_, E_,
        Xenc, H_, W1 + 2048, 3072, H_,
        (const TX*)nullptr, 0, nullptr, 0, 0,
        nullptr, 0,
        b1, nullptr, nullptr, nullptr, Xproj, E_);

    // ---- decoder (h=d)
    hipMemsetAsync(h, 0, (size_t)B_ * H_ * sizeof(float), stream);
    hipMemsetAsync(c, 0, (size_t)B_ * H_ * sizeof(float), stream);

    for (int t = 0; t < T_; ++t) {
        gemm<64, 64, 16, 4, 4, float, float><<<dim3(E_ / 64, B_ / 64), 256, 0, stream>>>(
            B_, E_,
            h, H_, W1, 3072, H_,
            c, H_, W1 + 1024, 3072, H_,
            nullptr, 0,
            nullptr, nullptr, nullptr, nullptr, pre, E_);
        dec_attn<TX><<<B_, 256, 0, stream>>>(pre, Xproj, Xenc, W2, b2, fc_w, fc_b,
                                             y_prev, t, ctx, ytil);
        gemm<128, 128, 16, 8, 8, float, float><<<dim3(G_ / 128, B_ / 128), 256, 0, stream>>>(
            B_, G_,
            h, H_, Whh_d, H_, H_,
            (const float*)nullptr, 0, nullptr, 0, 0,
            nullptr, 0,
            bih_d, bhh_d, ytil, Wih_d, gates, G_);
        lstm_pw<float><<<(B_ * H_) / 256, 256, 0, stream>>>(gates, h, c, nullptr, t);
    }

    final_out<<<B_, 256, 0, stream>>>(h, ctx, ff_w, ff_b, out);
}

extern "C" void kernel_launch(void* const* d_in, const int* in_sizes, int n_in,
                              void* d_out, int out_size, void* d_ws, size_t ws_size,
                              hipStream_t stream)
{
    auto au = [](size_t x) { return (x + 255) & ~(size_t)255; };
    const size_t fixed = au((size_t)B_ * I_ * 4)      // alpha
                       + au((size_t)B_ * G_ * 4)      // gates
                       + 4 * au((size_t)B_ * H_ * 4)  // h, c, pre, ctx
                       + 4096;                        // ytil + slack
    const size_t needF = fixed + 2 * au((size_t)B_ * T_ * H_ * 4);
    // lean need = fixed + 2 * au(B*T*H*2)  (~324 MiB)

    if (ws_size >= needF)
        run_pipeline<float>(d_in, (float*)d_out, (char*)d_ws, stream);
    else
        run_pipeline<unsigned short>(d_in, (float*)d_out, (char*)d_ws, stream);
}

// Round 4
// 10066.545 us; speedup vs baseline: 2.9061x; 2.9061x over previous
//
#include <hip/hip_runtime.h>
#include <cstddef>
#include <cstdint>

// DA-RNN for MI355X — round 4: bf16 MFMA GEMMs (16x16x32), T2 swizzle,
// global_load_lds width-16 staging. Fallback to R3's proven fp32-VALU lean
// path if ws_size < ~359 MiB (branch on constant ws_size: graph-safe).
// B=2048, T=32, I=512, H=D=E=1024, 4H=4096.
//
// R3 profile: Xproj fp32 GEMM 137GF @ 1.61ms = 85 TF (VALUBusy 62%, Mfma 0).
// Lean path ran -> 324 MiB <= ws_size < 610 MiB. absmax 4.88e-4 passed with
// bf16-stored Xenc/Xproj.

#define B_ 2048
#define T_ 32
#define I_ 512
#define H_ 1024
#define G_ 4096  // 4*H
#define E_ 1024

typedef unsigned short u16;
typedef float f32x4 __attribute__((ext_vector_type(4)));
typedef short bf16x8 __attribute__((ext_vector_type(8)));
typedef __attribute__((address_space(1))) const void gv_t;
typedef __attribute__((address_space(3))) void lv_t;

// ---- bf16 helpers (raw u16 storage; bf16 = top 16 bits of f32) -------------
__device__ __forceinline__ float bf2f(u16 u) {
    union { float f; unsigned v; } w; w.v = ((unsigned)u) << 16; return w.f;
}
__device__ __forceinline__ u16 f2bf(float f) {
    union { float f; unsigned v; } w; w.f = f;
    unsigned r = w.v + 0x7fff + ((w.v >> 16) & 1);  // round-to-nearest-even
    return (u16)(r >> 16);
}
template <typename T>
__device__ __forceinline__ float ld1(const T* p) {
    if constexpr (sizeof(T) == 4) return *(const float*)p;
    else return bf2f(*(const u16*)p);
}
template <typename T>
__device__ __forceinline__ float4 ld4(const T* p) {
    if constexpr (sizeof(T) == 4) {
        return *(const float4*)p;
    } else {
        const ushort4 u = *(const ushort4*)p;
        float4 r; r.x = bf2f(u.x); r.y = bf2f(u.y); r.z = bf2f(u.z); r.w = bf2f(u.w);
        return r;
    }
}

// ===========================================================================
// MFMA bf16 GEMM:  C[m,n] = sum_k A1[m,k]*B1[n,k] + sum_k A2[m,k]*B2[n,k]
//                           + bias1[n] + bias2[n] + u[m]*v[n]
// A,B row-major bf16 (B is N x K i.e. weights as stored) -> A @ B^T.
// 128xBN tile, BK=64, 4 waves (2x2), mfma_f32_16x16x32_bf16.
// LDS tiles [rows][64] bf16, 128 B/row, XOR-swizzled (T2) via pre-swizzled
// global source (rule #21: linear glds dest + inverse-swizzled source).
// ===========================================================================
__device__ __forceinline__ int lds_off(int row, int k) {  // k: elem idx in [0,64)
    return row * 128 + ((k * 2) ^ ((row & 7) << 4));
}

template <int ROWS>
__device__ __forceinline__ void stage_tile(char* lds, const u16* g,
                                           int row0, int ld, int k0, int tid)
{
    const int rb = tid >> 3, slot = tid & 7;
#pragma unroll
    for (int i = 0; i < ROWS / 32; ++i) {
        const int r = i * 32 + rb;                 // tile-local row
        const int ss = slot ^ (r & 7);             // inverse-swizzled source slot
        const u16* src = g + (size_t)(row0 + r) * ld + k0 + ss * 8;
        char* dst = lds + i * 4096 + (tid & 192) * 16;  // wave-uniform base
        __builtin_amdgcn_global_load_lds((gv_t*)src, (lv_t*)dst, 16, 0, 0);
    }
}

template <int BM, int BN, typename TC>
__global__ __launch_bounds__(256) void gemm_bf16(
    const u16* __restrict__ A1, int lda1, const u16* __restrict__ B1, int ldb1, int K1,
    const u16* __restrict__ A2, int lda2, const u16* __restrict__ B2, int ldb2, int K2,
    const float* __restrict__ bias1, const float* __restrict__ bias2,
    const float* __restrict__ u, const float* __restrict__ v,
    TC* __restrict__ C, int ldc)
{
    constexpr int FM = BM / 32, FN = BN / 32;      // frags per wave (2x2 waves)
    __shared__ __align__(16) char lds[(BM + BN) * 128];
    char* ldsA = lds;
    char* ldsB = lds + BM * 128;
    const int tid = threadIdx.x;
    const int lane = tid & 63, wid = tid >> 6;
    const int wm = wid >> 1, wn = wid & 1;
    const int bm = blockIdx.y * BM, bn = blockIdx.x * BN;

    f32x4 acc[FM][FN] = {};

    for (int pair = 0; pair < 2; ++pair) {
        const u16* A = pair ? A2 : A1;
        const u16* Bw = pair ? B2 : B1;
        const int lda = pair ? lda2 : lda1;
        const int ldb = pair ? ldb2 : ldb1;
        const int K = pair ? K2 : K1;
        if (K == 0) continue;
        for (int k0 = 0; k0 < K; k0 += 64) {
            stage_tile<BM>(ldsA, A, bm, lda, k0, tid);
            stage_tile<BN>(ldsB, Bw, bn, ldb, k0, tid);
            __syncthreads();   // compiler drains vmcnt before s_barrier
#pragma unroll
            for (int kk = 0; kk < 64; kk += 32) {
                const int krd = kk + (lane >> 4) * 8;
                bf16x8 af[FM], bfr[FN];
#pragma unroll
                for (int i = 0; i < FM; ++i)
                    af[i] = *(const bf16x8*)(ldsA +
                        lds_off(wm * FM * 16 + i * 16 + (lane & 15), krd));
#pragma unroll
                for (int j = 0; j < FN; ++j)
                    bfr[j] = *(const bf16x8*)(ldsB +
                        lds_off(wn * FN * 16 + j * 16 + (lane & 15), krd));
#pragma unroll
                for (int i = 0; i < FM; ++i)
#pragma unroll
                    for (int j = 0; j < FN; ++j)
                        acc[i][j] = __builtin_amdgcn_mfma_f32_16x16x32_bf16(
                            af[i], bfr[j], acc[i][j], 0, 0, 0);
            }
            __syncthreads();
        }
    }

    // epilogue — C/D layout: col=lane&15, row=(lane>>4)*4+reg  [m89 verified]
#pragma unroll
    for (int j = 0; j < FN; ++j) {
        const int col = bn + wn * FN * 16 + j * 16 + (lane & 15);
        const float bsum = (bias1 ? bias1[col] : 0.f) + (bias2 ? bias2[col] : 0.f);
        const float vv = v ? v[col] : 0.f;
#pragma unroll
        for (int i = 0; i < FM; ++i) {
#pragma unroll
            for (int r = 0; r < 4; ++r) {
                const int row = bm + wm * FM * 16 + i * 16 + (lane >> 4) * 4 + r;
                float val = acc[i][j][r] + bsum;
                if (u) val += u[row] * vv;
                if constexpr (sizeof(TC) == 4)
                    ((float*)C)[(size_t)row * ldc + col] = val;
                else
                    ((u16*)C)[(size_t)row * ldc + col] = f2bf(val);
            }
        }
    }
}

// ===========================================================================
// Prep kernels
// ===========================================================================
__global__ __launch_bounds__(256) void attn_prep(
    const float* __restrict__ X, const float* __restrict__ eaw, float* __restrict__ alpha)
{
    const int b = blockIdx.x, tid = threadIdx.x;
    __shared__ float wx[T_];
    __shared__ float red[4];
    if (tid < T_) wx[tid] = eaw[2 * H_ + tid];
    __syncthreads();
    const float* xb = X + (size_t)b * T_ * I_;
    float a0 = 0.0f, a1 = 0.0f;
#pragma unroll
    for (int t = 0; t < T_; ++t) {
        a0 = fmaf(xb[t * I_ + tid], wx[t], a0);
        a1 = fmaf(xb[t * I_ + tid + 256], wx[t], a1);
    }
    float m = fmaxf(a0, a1);
#pragma unroll
    for (int off = 32; off; off >>= 1) m = fmaxf(m, __shfl_down(m, off));
    if ((tid & 63) == 0) red[tid >> 6] = m;
    __syncthreads();
    m = fmaxf(fmaxf(red[0], red[1]), fmaxf(red[2], red[3]));
    __syncthreads();
    const float e0 = expf(a0 - m), e1 = expf(a1 - m);
    float ssum = e0 + e1;
#pragma unroll
    for (int off = 32; off; off >>= 1) ssum += __shfl_down(ssum, off);
    if ((tid & 63) == 0) red[tid >> 6] = ssum;
    __syncthreads();
    const float inv = 1.0f / (red[0] + red[1] + red[2] + red[3]);
    alpha[(size_t)b * I_ + tid]       = e0 * inv;
    alpha[(size_t)b * I_ + tid + 256] = e1 * inv;
}

// Xt[(t*B+b)*I+i] = bf16(alpha[b,i] * X[b,t,i])
__global__ __launch_bounds__(256) void build_xt(
    const float* __restrict__ X, const float* __restrict__ alpha, u16* __restrict__ Xt)
{
    const int il = blockIdx.x * 256 + threadIdx.x;  // b*I + i
    const int t = blockIdx.y;
    const int b = il >> 9, i = il & 511;
    const float val = alpha[il] * X[(((size_t)b * T_ + t) << 9) + i];
    Xt[((size_t)t * B_ + b) * I_ + i] = f2bf(val);
}

__global__ __launch_bounds__(256) void f2bf_copy(
    const float* __restrict__ src, u16* __restrict__ dst, int n4)
{
    const int id = blockIdx.x * 256 + threadIdx.x;
    if (id >= n4) return;
    const float4 v = *(const float4*)(src + (size_t)id * 4);
    ushort4 s; s.x = f2bf(v.x); s.y = f2bf(v.y); s.z = f2bf(v.z); s.w = f2bf(v.w);
    *(ushort4*)(dst + (size_t)id * 4) = s;
}

// W1 (1024 x 3072) -> W1dc bf16 (1024 x 2048) + W1x bf16 (1024 x 1024)
__global__ __launch_bounds__(256) void split_w1(
    const float* __restrict__ W1, u16* __restrict__ W1dc, u16* __restrict__ W1x)
{
    const int id = blockIdx.x * 256 + threadIdx.x;  // < 1024*768
    const int f = id / 768, c4 = (id % 768) * 4;
    const float4 v = *(const float4*)(W1 + (size_t)f * 3072 + c4);
    ushort4 s; s.x = f2bf(v.x); s.y = f2bf(v.y); s.z = f2bf(v.z); s.w = f2bf(v.w);
    if (c4 < 2048) *(ushort4*)(W1dc + (size_t)f * 2048 + c4) = s;
    else           *(ushort4*)(W1x  + (size_t)f * 1024 + (c4 - 2048)) = s;
}

// ===========================================================================
// LSTM pointwise: fp32 states + bf16 shadow copies; optional Xenc / c_bf.
// ===========================================================================
__global__ __launch_bounds__(256) void lstm_pw2(
    const float* __restrict__ gates, float* __restrict__ h, float* __restrict__ c,
    u16* __restrict__ h_bf, u16* __restrict__ c_bf, u16* __restrict__ xenc, int t)
{
    const size_t idx = (size_t)blockIdx.x * 256 + threadIdx.x;  // < B*H
    const int b = (int)(idx >> 10);
    const int j = (int)(idx & 1023);
    const float* g = gates + ((size_t)b << 12);
    const float gi = g[j], gf = g[j + 1024], gg = g[j + 2048], go = g[j + 3072];
    const float si = 1.0f / (1.0f + expf(-gi));
    const float sf = 1.0f / (1.0f + expf(-gf));
    const float so = 1.0f / (1.0f + expf(-go));
    const float cn = sf * c[idx] + si * tanhf(gg);
    const float hn = so * tanhf(cn);
    c[idx] = cn;
    h[idx] = hn;
    h_bf[idx] = f2bf(hn);
    if (c_bf) c_bf[idx] = f2bf(cn);
    if (xenc) xenc[(((size_t)b * T_ + t) << 10) + j] = hn == hn ? f2bf(hn) : 0;
}

// ===========================================================================
// Fused decoder attention step (reads bf16 Xproj/Xenc, fp32 pre)
// ===========================================================================
template <typename TX>
__global__ __launch_bounds__(256) void dec_attn(
    const float* __restrict__ pre, const TX* __restrict__ Xproj,
    const TX* __restrict__ Xenc, const float* __restrict__ W2,
    const float* __restrict__ b2, const float* __restrict__ fc_w,
    const float* __restrict__ fc_b, const float* __restrict__ y_prev,
    int step, float* __restrict__ ctx, float* __restrict__ ytil)
{
    const int b = blockIdx.x, tid = threadIdx.x;
    __shared__ float red[4];
    __shared__ float sc[T_];
    float pr[4], w2r[4];
#pragma unroll
    for (int q = 0; q < 4; ++q) {
        pr[q]  = pre[(size_t)b * 1024 + tid + 256 * q];
        w2r[q] = W2[tid + 256 * q];
    }
    const TX* xp = Xproj + (size_t)b * T_ * 1024;
    for (int t = 0; t < T_; ++t) {
        float s = 0.0f;
#pragma unroll
        for (int q = 0; q < 4; ++q)
            s += tanhf(pr[q] + ld1(xp + t * 1024 + tid + 256 * q)) * w2r[q];
#pragma unroll
        for (int off = 32; off; off >>= 1) s += __shfl_down(s, off);
        if ((tid & 63) == 0) red[tid >> 6] = s;
        __syncthreads();
        if (tid == 0) sc[t] = red[0] + red[1] + red[2] + red[3] + b2[0];
        __syncthreads();
    }
    float mx = -1e30f;
#pragma unroll
    for (int t = 0; t < T_; ++t) mx = fmaxf(mx, sc[t]);
    float beta[T_];
    float ssum = 0.0f;
#pragma unroll
    for (int t = 0; t < T_; ++t) { beta[t] = expf(sc[t] - mx); ssum += beta[t]; }
    const float inv = 1.0f / ssum;
    const TX* xe = Xenc + (size_t)b * T_ * 1024;
    float cx[4] = {0.0f, 0.0f, 0.0f, 0.0f};
    for (int t = 0; t < T_; ++t) {
        const float bt = beta[t];
#pragma unroll
        for (int q = 0; q < 4; ++q)
            cx[q] = fmaf(bt, ld1(xe + t * 1024 + tid + 256 * q), cx[q]);
    }
    float yt = 0.0f;
#pragma unroll
    for (int q = 0; q < 4; ++q) {
        const float cv = cx[q] * inv;
        ctx[(size_t)b * 1024 + tid + 256 * q] = cv;
        yt += cv * fc_w[tid + 256 * q];
    }
#pragma unroll
    for (int off = 32; off; off >>= 1) yt += __shfl_down(yt, off);
    if ((tid & 63) == 0) red[tid >> 6] = yt;
    __syncthreads();
    if (tid == 0)
        ytil[b] = red[0] + red[1] + red[2] + red[3]
                + y_prev[(size_t)b * T_ + step] * fc_w[1024] + fc_b[0];
}

__global__ __launch_bounds__(256) void final_out(
    const float* __restrict__ d, const float* __restrict__ ctx,
    const float* __restrict__ ffw, const float* __restrict__ ffb,
    float* __restrict__ out)
{
    const int b = blockIdx.x, tid = threadIdx.x;
    float s = 0.0f;
#pragma unroll
    for (int q = 0; q < 4; ++q) {
        const int e = tid + 256 * q;
        s += d[(size_t)b * 1024 + e] * ffw[e] + ctx[(size_t)b * 1024 + e] * ffw[1024 + e];
    }
#pragma unroll
    for (int off = 32; off; off >>= 1) s += __shfl_down(s, off);
    __shared__ float red[4];
    if ((tid & 63) == 0) red[tid >> 6] = s;
    __syncthreads();
    if (tid == 0) out[b] = red[0] + red[1] + red[2] + red[3] + ffb[0];
}

// ===========================================================================
// Fallback fp32-VALU GEMM (R3, proven) — used only if ws_size too small
// ===========================================================================
template <int BM, int BN, int BK, int TM, int TN, typename TA, typename TC>
__global__ __launch_bounds__(256) void gemm(
    int M, int N,
    const TA* __restrict__ A1, int lda1, const float* __restrict__ B1, int ldb1, int K1,
    const TA* __restrict__ A2, int lda2, const float* __restrict__ B2, int ldb2, int K2,
    const float* __restrict__ ascale, int ldsc,
    const float* __restrict__ bias1, const float* __restrict__ bias2,
    const float* __restrict__ u, const float* __restrict__ v,
    TC* __restrict__ C, int ldc)
{
    constexpr int TCOLS = BN / TN;
    constexpr int KCH = BK / 4;
    constexpr int ROWS_PER_PASS = 256 / KCH;

    __shared__ float As[BK][BM + 4];
    __shared__ float Bs[BK][BN + 4];

    const int tid = threadIdx.x;
    const int tn = tid % TCOLS;
    const int tm = tid / TCOLS;
    const int bn = blockIdx.x * BN;
    const int bm = blockIdx.y * BM;
    const int lrow = tid / KCH;
    const int lkc  = (tid % KCH) * 4;

    float acc[TM][TN];
#pragma unroll
    for (int i = 0; i < TM; ++i)
#pragma unroll
        for (int j = 0; j < TN; ++j) acc[i][j] = 0.0f;

    for (int pair = 0; pair < 2; ++pair) {
        const TA* A  = pair ? A2 : A1;
        const float* Bp = pair ? B2 : B1;
        const float* sc = pair ? nullptr : ascale;
        const int lda = pair ? lda2 : lda1;
        const int ldb = pair ? ldb2 : ldb1;
        const int K   = pair ? K2 : K1;
        if (K == 0) continue;
        for (int k0 = 0; k0 < K; k0 += BK) {
            __syncthreads();
#pragma unroll
            for (int r = 0; r < BM; r += ROWS_PER_PASS) {
                const int row = bm + r + lrow;
                float4 val = ld4(A + (size_t)row * lda + (k0 + lkc));
                if (sc) {
                    const float4 s = *(const float4*)(sc + (size_t)row * ldsc + (k0 + lkc));
                    val.x *= s.x; val.y *= s.y; val.z *= s.z; val.w *= s.w;
                }
                As[lkc + 0][r + lrow] = val.x;
                As[lkc + 1][r + lrow] = val.y;
                As[lkc + 2][r + lrow] = val.z;
                As[lkc + 3][r + lrow] = val.w;
            }
#pragma unroll
            for (int r = 0; r < BN; r += ROWS_PER_PASS) {
                const float4 val = *(const float4*)(Bp + (size_t)(bn + r + lrow) * ldb + (k0 + lkc));
                Bs[lkc + 0][r + lrow] = val.x;
                Bs[lkc + 1][r + lrow] = val.y;
                Bs[lkc + 2][r + lrow] = val.z;
                Bs[lkc + 3][r + lrow] = val.w;
            }
            __syncthreads();
#pragma unroll
            for (int k = 0; k < BK; ++k) {
                float a[TM], bv[TN];
#pragma unroll
                for (int i = 0; i < TM; ++i) a[i] = As[k][tm * TM + i];
#pragma unroll
                for (int j = 0; j < TN; ++j) bv[j] = Bs[k][tn * TN + j];
#pragma unroll
                for (int i = 0; i < TM; ++i)
#pragma unroll
                    for (int j = 0; j < TN; ++j)
                        acc[i][j] = fmaf(a[i], bv[j], acc[i][j]);
            }
        }
    }

#pragma unroll
    for (int i = 0; i < TM; ++i) {
        const int m = bm + tm * TM + i;
        const float um = u ? u[m] : 0.0f;
#pragma unroll
        for (int j = 0; j < TN; j += 4) {
            const int n = bn + tn * TN + j;
            float r[4];
#pragma unroll
            for (int q = 0; q < 4; ++q) {
                float val = acc[i][j + q];
                if (bias1) val += bias1[n + q];
                if (bias2) val += bias2[n + q];
                if (u)     val += um * v[n + q];
                r[q] = val;
            }
            if constexpr (sizeof(TC) == 4) {
                float4 f; f.x = r[0]; f.y = r[1]; f.z = r[2]; f.w = r[3];
                *(float4*)((float*)C + (size_t)m * ldc + n) = f;
            } else {
                ushort4 s;
                s.x = f2bf(r[0]); s.y = f2bf(r[1]); s.z = f2bf(r[2]); s.w = f2bf(r[3]);
                *(ushort4*)((u16*)C + (size_t)m * ldc + n) = s;
            }
        }
    }
}

template <typename TX>
__global__ __launch_bounds__(256) void lstm_pw(
    const float* __restrict__ gates, float* __restrict__ h, float* __restrict__ c,
    TX* __restrict__ xenc, int t)
{
    const size_t idx = (size_t)blockIdx.x * 256 + threadIdx.x;
    const int b = (int)(idx >> 10);
    const int j = (int)(idx & 1023);
    const float* g = gates + ((size_t)b << 12);
    const float gi = g[j], gf = g[j + 1024], gg = g[j + 2048], go = g[j + 3072];
    const float si = 1.0f / (1.0f + expf(-gi));
    const float sf = 1.0f / (1.0f + expf(-gf));
    const float so = 1.0f / (1.0f + expf(-go));
    const float cn = sf * c[idx] + si * tanhf(gg);
    const float hn = so * tanhf(cn);
    c[idx] = cn;
    h[idx] = hn;
    if (xenc) {
        if constexpr (sizeof(TX) == 4) ((float*)xenc)[(((size_t)b * T_ + t) << 10) + j] = hn;
        else ((u16*)xenc)[(((size_t)b * T_ + t) << 10) + j] = f2bf(hn);
    }
}

// ===========================================================================
static void run_mfma(void* const* d_in, float* out, char* ws, hipStream_t stream)
{
    const float* X      = (const float*)d_in[0];
    const float* y_prev = (const float*)d_in[1];
    const float* eaw    = (const float*)d_in[2];
    const float* Wih_e  = (const float*)d_in[4];
    const float* Whh_e  = (const float*)d_in[5];
    const float* bih_e  = (const float*)d_in[6];
    const float* bhh_e  = (const float*)d_in[7];
    const float* W1     = (const float*)d_in[8];
    const float* b1     = (const float*)d_in[9];
    const float* W2     = (const float*)d_in[10];
    const float* b2     = (const float*)d_in[11];
    const float* Wih_d  = (const float*)d_in[12];
    const float* bih_d  = (const float*)d_in[14];
    const float* bhh_d  = (const float*)d_in[15];
    const float* Whh_d  = (const float*)d_in[13];
    const float* fc_w   = (const float*)d_in[16];
    const float* fc_b   = (const float*)d_in[17];
    const float* ff_w   = (const float*)d_in[18];
    const float* ff_b   = (const float*)d_in[19];

    auto au = [](size_t x) { return (x + 255) & ~(size_t)255; };
    char* p = ws;
    u16* Xenc   = (u16*)p;   p += au((size_t)B_ * T_ * H_ * 2);   // 134 MB
    u16* Xt     = (u16*)p;                                        // union:
    u16* Xproj  = (u16*)p;   p += au((size_t)B_ * T_ * H_ * 2);   // 134 MB
    float* gates = (float*)p; p += au((size_t)B_ * G_ * 4);       // 33.5 MB
    float* h    = (float*)p; p += au((size_t)B_ * H_ * 4);
    float* c    = (float*)p; p += au((size_t)B_ * H_ * 4);
    u16* h_bf   = (u16*)p;   p += au((size_t)B_ * H_ * 2);
    u16* c_bf   = (u16*)p;   p += au((size_t)B_ * H_ * 2);
    float* pre  = (float*)p; p += au((size_t)B_ * E_ * 4);
    float* ctx  = (float*)p; p += au((size_t)B_ * E_ * 4);
    u16* Wih_e_bf = (u16*)p; p += au((size_t)G_ * I_ * 2);
    u16* Whh_e_bf = (u16*)p; p += au((size_t)G_ * H_ * 2);
    u16* Whh_d_bf = (u16*)p; p += au((size_t)G_ * H_ * 2);
    u16* W1dc_bf  = (u16*)p; p += au((size_t)E_ * 2048 * 2);
    u16* W1x_bf   = (u16*)p; p += au((size_t)E_ * 1024 * 2);
    float* alpha  = (float*)p; p += au((size_t)B_ * I_ * 4);
    float* ytil   = (float*)p;

    // weight conversions
    f2bf_copy<<<(G_ * I_ / 4 + 255) / 256, 256, 0, stream>>>(Wih_e, Wih_e_bf, G_ * I_ / 4);
    f2bf_copy<<<(G_ * H_ / 4 + 255) / 256, 256, 0, stream>>>(Whh_e, Whh_e_bf, G_ * H_ / 4);
    f2bf_copy<<<(G_ * H_ / 4 + 255) / 256, 256, 0, stream>>>(Whh_d, Whh_d_bf, G_ * H_ / 4);
    split_w1<<<(E_ * 768) / 256, 256, 0, stream>>>(W1, W1dc_bf, W1x_bf);

    hipMemsetAsync(h, 0, (size_t)B_ * H_ * 4, stream);
    hipMemsetAsync(c, 0, (size_t)B_ * H_ * 4, stream);
    hipMemsetAsync(h_bf, 0, (size_t)B_ * H_ * 2, stream);

    attn_prep<<<B_, 256, 0, stream>>>(X, eaw, alpha);
    build_xt<<<dim3(B_ * I_ / 256, T_), 256, 0, stream>>>(X, alpha, Xt);

    // ---- encoder: gates = Xt_t @ Wih_e^T + h @ Whh_e^T + biases
    for (int t = 0; t < T_; ++t) {
        gemm_bf16<128, 128, float><<<dim3(G_ / 128, B_ / 128), 256, 0, stream>>>(
            Xt + (size_t)t * B_ * I_, I_, Wih_e_bf, I_, I_,
            h_bf, H_, Whh_e_bf, H_, H_,
            bih_e, bhh_e, nullptr, nullptr, gates, G_);
        lstm_pw2<<<(B_ * H_) / 256, 256, 0, stream>>>(gates, h, c, h_bf, nullptr, Xenc, t);
    }

    // ---- Xproj = Xenc @ W1x^T + b1   (overwrites Xt union region; Xt dead)
    gemm_bf16<128, 128, u16><<<dim3(E_ / 128, (B_ * T_) / 128), 256, 0, stream>>>(
        Xenc, H_, W1x_bf, H_, H_,
        nullptr, 0, nullptr, 0, 0,
        b1, nullptr, nullptr, nullptr, Xproj, E_);

    // ---- decoder (h = d)
    hipMemsetAsync(h, 0, (size_t)B_ * H_ * 4, stream);
    hipMemsetAsync(c, 0, (size_t)B_ * H_ * 4, stream);
    hipMemsetAsync(h_bf, 0, (size_t)B_ * H_ * 2, stream);
    hipMemsetAsync(c_bf, 0, (size_t)B_ * H_ * 2, stream);

    for (int t = 0; t < T_; ++t) {
        // pre = d @ W1[:, :1024]^T + c @ W1[:, 1024:2048]^T
        gemm_bf16<128, 64, float><<<dim3(E_ / 64, B_ / 128), 256, 0, stream>>>(
            h_bf, H_, W1dc_bf, 2048, H_,
            c_bf, H_, W1dc_bf + 1024, 2048, H_,
            nullptr, nullptr, nullptr, nullptr, pre, E_);
        dec_attn<u16><<<B_, 256, 0, stream>>>(pre, Xproj, Xenc, W2, b2, fc_w, fc_b,
                                              y_prev, t, ctx, ytil);
        // gates = d @ Whh_d^T + bih_d + bhh_d + ytil[m]*Wih_d[n]
        gemm_bf16<128, 128, float><<<dim3(G_ / 128, B_ / 128), 256, 0, stream>>>(
            h_bf, H_, Whh_d_bf, H_, H_,
            nullptr, 0, nullptr, 0, 0,
            bih_d, bhh_d, ytil, Wih_d, gates, G_);
        lstm_pw2<<<(B_ * H_) / 256, 256, 0, stream>>>(gates, h, c, h_bf, c_bf, nullptr, t);
    }

    final_out<<<B_, 256, 0, stream>>>(h, ctx, ff_w, ff_b, out);
}

// ---- R3 lean fallback ------------------------------------------------------
static void run_fallback(void* const* d_in, float* out, char* ws, hipStream_t stream)
{
    const float* X      = (const float*)d_in[0];
    const float* y_prev = (const float*)d_in[1];
    const float* eaw    = (const float*)d_in[2];
    const float* Wih_e  = (const float*)d_in[4];
    const float* Whh_e  = (const float*)d_in[5];
    const float* bih_e  = (const float*)d_in[6];
    const float* bhh_e  = (const float*)d_in[7];
    const float* W1     = (const float*)d_in[8];
    const float* b1     = (const float*)d_in[9];
    const float* W2     = (const float*)d_in[10];
    const float* b2     = (const float*)d_in[11];
    const float* Wih_d  = (const float*)d_in[12];
    const float* Whh_d  = (const float*)d_in[13];
    const float* bih_d  = (const float*)d_in[14];
    const float* bhh_d  = (const float*)d_in[15];
    const float* fc_w   = (const float*)d_in[16];
    const float* fc_b   = (const float*)d_in[17];
    const float* ff_w   = (const float*)d_in[18];
    const float* ff_b   = (const float*)d_in[19];

    auto au = [](size_t x) { return (x + 255) & ~(size_t)255; };
    char* p = ws;
    float* alpha = (float*)p;  p += au((size_t)B_ * I_ * 4);
    u16*   Xenc  = (u16*)p;    p += au((size_t)B_ * T_ * H_ * 2);
    u16*   Xproj = (u16*)p;    p += au((size_t)B_ * T_ * H_ * 2);
    float* gates = (float*)p;  p += au((size_t)B_ * G_ * 4);
    float* h     = (float*)p;  p += au((size_t)B_ * H_ * 4);
    float* c     = (float*)p;  p += au((size_t)B_ * H_ * 4);
    float* pre   = (float*)p;  p += au((size_t)B_ * E_ * 4);
    float* ctx   = (float*)p;  p += au((size_t)B_ * E_ * 4);
    float* ytil  = (float*)p;

    hipMemsetAsync(h, 0, (size_t)B_ * H_ * 4, stream);
    hipMemsetAsync(c, 0, (size_t)B_ * H_ * 4, stream);

    attn_prep<<<B_, 256, 0, stream>>>(X, eaw, alpha);

    for (int t = 0; t < T_; ++t) {
        gemm<128, 128, 16, 8, 8, float, float><<<dim3(G_ / 128, B_ / 128), 256, 0, stream>>>(
            B_, G_,
            X + (size_t)t * I_, T_ * I_, Wih_e, I_, I_,
            h, H_, Whh_e, H_, H_,
            alpha, I_,
            bih_e, bhh_e, nullptr, nullptr, gates, G_);
        lstm_pw<u16><<<(B_ * H_) / 256, 256, 0, stream>>>(gates, h, c, Xenc, t);
    }

    gemm<128, 128, 16, 8, 8, u16, u16><<<dim3(E_ / 128, (B_ * T_) / 128), 256, 0, stream>>>(
        B_ * T_, E_,
        Xenc, H_, W1 + 2048, 3072, H_,
        (const u16*)nullptr, 0, nullptr, 0, 0,
        nullptr, 0,
        b1, nullptr, nullptr, nullptr, Xproj, E_);

    hipMemsetAsync(h, 0, (size_t)B_ * H_ * 4, stream);
    hipMemsetAsync(c, 0, (size_t)B_ * H_ * 4, stream);

    for (int t = 0; t < T_; ++t) {
        gemm<64, 64, 16, 4, 4, float, float><<<dim3(E_ / 64, B_ / 64), 256, 0, stream>>>(
            B_, E_,
            h, H_, W1, 3072, H_,
            c, H_, W1 + 1024, 3072, H_,
            nullptr, 0,
            nullptr, nullptr, nullptr, nullptr, pre, E_);
        dec_attn<u16><<<B_, 256, 0, stream>>>(pre, Xproj, Xenc, W2, b2, fc_w, fc_b,
                                              y_prev, t, ctx, ytil);
        gemm<128, 128, 16, 8, 8, float, float><<<dim3(G_ / 128, B_ / 128), 256, 0, stream>>>(
            B_, G_,
            h, H_, Whh_d, H_, H_,
            (const float*)nullptr, 0, nullptr, 0, 0,
            nullptr, 0,
            bih_d, bhh_d, ytil, Wih_d, gates, G_);
        lstm_pw<float><<<(B_ * H_) / 256, 256, 0, stream>>>(gates, h, c, nullptr, t);
    }

    final_out<<<B_, 256, 0, stream>>>(h, ctx, ff_w, ff_b, out);
}

extern "C" void kernel_launch(void* const* d_in, const int* in_sizes, int n_in,
                              void* d_out, int out_size, void* d_ws, size_t ws_size,
                              hipStream_t stream)
{
    auto au = [](size_t x) { return (x + 255) & ~(size_t)255; };
    const size_t needM =
        2 * au((size_t)B_ * T_ * H_ * 2) +   // Xenc + (Xt|Xproj union)
        au((size_t)B_ * G_ * 4) +            // gates
        2 * au((size_t)B_ * H_ * 4) +        // h, c
        2 * au((size_t)B_ * H_ * 2) +        // h_bf, c_bf
        2 * au((size_t)B_ * E_ * 4) +        // pre, ctx
        au((size_t)G_ * I_ * 2) + 2 * au((size_t)G_ * H_ * 2) +
        au((size_t)E_ * 2048 * 2) + au((size_t)E_ * 1024 * 2) +  // weights bf16
        au((size_t)B_ * I_ * 4) +            // alpha
        au((size_t)B_ * 4) + 4096;           // ytil + slack

    if (ws_size >= needM)
        run_mfma(d_in, (float*)d_out, (char*)d_ws, stream);
    else
        run_fallback(d_in, (float*)d_out, (char*)d_ws, stream);
}

// Round 5
// 6636.307 us; speedup vs baseline: 4.4082x; 1.5169x over previous
//
#include <hip/hip_runtime.h>
#include <cstddef>
#include <cstdint>

// DA-RNN for MI355X — round 5: fuse LSTM into gates-GEMM epilogue via
// gate-interleaved weight permutation; vectorize dec_attn (ushort4 loads,
// 1 barrier). R4: 10.07 ms, MFMA path proven, swizzle conflict-free,
// Xproj gemm = 723 TF. ws_size >= ~375 MB proven.
// B=2048, T=32, I=512, H=D=E=1024, 4H=4096.

#define B_ 2048
#define T_ 32
#define I_ 512
#define H_ 1024
#define G_ 4096  // 4*H
#define E_ 1024

typedef unsigned short u16;
typedef float f32x4 __attribute__((ext_vector_type(4)));
typedef short bf16x8 __attribute__((ext_vector_type(8)));
typedef __attribute__((address_space(1))) const void gv_t;
typedef __attribute__((address_space(3))) void lv_t;

// ---- bf16 helpers ----------------------------------------------------------
__device__ __forceinline__ float bf2f(u16 u) {
    union { float f; unsigned v; } w; w.v = ((unsigned)u) << 16; return w.f;
}
__device__ __forceinline__ u16 f2bf(float f) {
    union { float f; unsigned v; } w; w.f = f;
    unsigned r = w.v + 0x7fff + ((w.v >> 16) & 1);
    return (u16)(r >> 16);
}
template <typename T>
__device__ __forceinline__ float ld1(const T* p) {
    if constexpr (sizeof(T) == 4) return *(const float*)p;
    else return bf2f(*(const u16*)p);
}
template <typename T>
__device__ __forceinline__ float4 ld4(const T* p) {
    if constexpr (sizeof(T) == 4) {
        return *(const float4*)p;
    } else {
        const ushort4 u = *(const ushort4*)p;
        float4 r; r.x = bf2f(u.x); r.y = bf2f(u.y); r.z = bf2f(u.z); r.w = bf2f(u.w);
        return r;
    }
}
__device__ __forceinline__ float tf(float x) {        // tanh via hw exp
    const float e = __expf(2.0f * x);
    return 1.0f - 2.0f / (e + 1.0f);
}
__device__ __forceinline__ float sg(float x) {        // sigmoid
    return 1.0f / (1.0f + __expf(-x));
}

// ---- LDS swizzle (T2, proven conflict-free in R4) --------------------------
__device__ __forceinline__ int lds_off(int row, int k) {  // k: elem in [0,64)
    return row * 128 + ((k * 2) ^ ((row & 7) << 4));
}

template <int ROWS>
__device__ __forceinline__ void stage_tile(char* lds, const u16* g,
                                           int row0, int ld, int k0, int tid)
{
    const int rb = tid >> 3, slot = tid & 7;
#pragma unroll
    for (int i = 0; i < ROWS / 32; ++i) {
        const int r = i * 32 + rb;
        const int ss = slot ^ (r & 7);             // inverse-swizzled source
        const u16* src = g + (size_t)(row0 + r) * ld + k0 + ss * 8;
        char* dst = lds + i * 4096 + (tid & 192) * 16;  // wave-uniform base
        __builtin_amdgcn_global_load_lds((gv_t*)src, (lv_t*)dst, 16, 0, 0);
    }
}

// ===========================================================================
// Plain MFMA GEMM (Xproj + decoder pre): C = A1@B1^T + A2@B2^T + bias1
// ===========================================================================
template <int BM, int BN, typename TC>
__global__ __launch_bounds__(256) void gemm_bf16(
    const u16* __restrict__ A1, int lda1, const u16* __restrict__ B1, int ldb1, int K1,
    const u16* __restrict__ A2, int lda2, const u16* __restrict__ B2, int ldb2, int K2,
    const float* __restrict__ bias1, const float* __restrict__ bias2,
    const float* __restrict__ u, const float* __restrict__ v,
    TC* __restrict__ C, int ldc)
{
    constexpr int FM = BM / 32, FN = BN / 32;
    __shared__ __align__(16) char lds[(BM + BN) * 128];
    char* ldsA = lds;
    char* ldsB = lds + BM * 128;
    const int tid = threadIdx.x;
    const int lane = tid & 63, wid = tid >> 6;
    const int wm = wid >> 1, wn = wid & 1;
    const int bm = blockIdx.y * BM, bn = blockIdx.x * BN;

    f32x4 acc[FM][FN] = {};

    for (int pair = 0; pair < 2; ++pair) {
        const u16* A = pair ? A2 : A1;
        const u16* Bw = pair ? B2 : B1;
        const int lda = pair ? lda2 : lda1;
        const int ldb = pair ? ldb2 : ldb1;
        const int K = pair ? K2 : K1;
        if (K == 0) continue;
        for (int k0 = 0; k0 < K; k0 += 64) {
            stage_tile<BM>(ldsA, A, bm, lda, k0, tid);
            stage_tile<BN>(ldsB, Bw, bn, ldb, k0, tid);
            __syncthreads();
#pragma unroll
            for (int kk = 0; kk < 64; kk += 32) {
                const int krd = kk + (lane >> 4) * 8;
                bf16x8 af[FM], bfr[FN];
#pragma unroll
                for (int i = 0; i < FM; ++i)
                    af[i] = *(const bf16x8*)(ldsA +
                        lds_off(wm * FM * 16 + i * 16 + (lane & 15), krd));
#pragma unroll
                for (int j = 0; j < FN; ++j)
                    bfr[j] = *(const bf16x8*)(ldsB +
                        lds_off(wn * FN * 16 + j * 16 + (lane & 15), krd));
#pragma unroll
                for (int i = 0; i < FM; ++i)
#pragma unroll
                    for (int j = 0; j < FN; ++j)
                        acc[i][j] = __builtin_amdgcn_mfma_f32_16x16x32_bf16(
                            af[i], bfr[j], acc[i][j], 0, 0, 0);
            }
            __syncthreads();
        }
    }

#pragma unroll
    for (int j = 0; j < FN; ++j) {
        const int col = bn + wn * FN * 16 + j * 16 + (lane & 15);
        const float bsum = (bias1 ? bias1[col] : 0.f) + (bias2 ? bias2[col] : 0.f);
        const float vv = v ? v[col] : 0.f;
#pragma unroll
        for (int i = 0; i < FM; ++i) {
#pragma unroll
            for (int r = 0; r < 4; ++r) {
                const int row = bm + wm * FM * 16 + i * 16 + (lane >> 4) * 4 + r;
                float val = acc[i][j][r] + bsum;
                if (u) val += u[row] * vv;
                if constexpr (sizeof(TC) == 4)
                    ((float*)C)[(size_t)row * ldc + col] = val;
                else
                    ((u16*)C)[(size_t)row * ldc + col] = f2bf(val);
            }
        }
    }
}

// ===========================================================================
// Fused gates-GEMM + LSTM. Weights pre-permuted: source row n=gate*1024+j
// lands at n' = (j>>4)*64 + gate*16 + (j&15), so the wave's 4 N-frags are
// the 4 gates of the same 16 j's -> same lane holds i,f,g,o. Tile 256x64,
// 4 waves on M. Reads h_bf_in (prev state), writes h_bf_out (double-buffer:
// cross-block RAW hazard), c fp32 in-place (thread-owned), optional Xenc
// (encoder) or h/c_bf (decoder). Decoder adds rank-1 ytil[m]*wv_p[n'].
// ===========================================================================
template <bool ENC>
__global__ __launch_bounds__(256) void gemm_lstm(
    const u16* __restrict__ A1, int lda1, const u16* __restrict__ B1, int K1,
    const u16* __restrict__ A2, int lda2, const u16* __restrict__ B2, int K2,
    const float* __restrict__ bias_p, const float* __restrict__ u,
    const float* __restrict__ v_p,
    float* __restrict__ c, float* __restrict__ h,
    u16* __restrict__ h_bf_out, u16* __restrict__ c_bf,
    u16* __restrict__ xenc, int t)
{
    __shared__ __align__(16) char lds[(256 + 64) * 128];
    char* ldsA = lds;
    char* ldsB = lds + 256 * 128;
    const int tid = threadIdx.x, lane = tid & 63, wid = tid >> 6;
    const int bm = blockIdx.y * 256, jg = blockIdx.x;

    f32x4 acc[4][4] = {};

    for (int pair = 0; pair < 2; ++pair) {
        const u16* A = pair ? A2 : A1;
        const u16* Bw = pair ? B2 : B1;
        const int lda = pair ? lda2 : lda1;
        const int K = pair ? K2 : K1;
        if (K == 0) continue;
        for (int k0 = 0; k0 < K; k0 += 64) {
            stage_tile<256>(ldsA, A, bm, lda, k0, tid);
            stage_tile<64>(ldsB, Bw, jg * 64, K, k0, tid);
            __syncthreads();
#pragma unroll
            for (int kk = 0; kk < 64; kk += 32) {
                const int krd = kk + (lane >> 4) * 8;
                bf16x8 af[4], bfr[4];
#pragma unroll
                for (int i = 0; i < 4; ++i)
                    af[i] = *(const bf16x8*)(ldsA +
                        lds_off(wid * 64 + i * 16 + (lane & 15), krd));
#pragma unroll
                for (int g = 0; g < 4; ++g)
                    bfr[g] = *(const bf16x8*)(ldsB +
                        lds_off(g * 16 + (lane & 15), krd));
#pragma unroll
                for (int i = 0; i < 4; ++i)
#pragma unroll
                    for (int g = 0; g < 4; ++g)
                        acc[i][g] = __builtin_amdgcn_mfma_f32_16x16x32_bf16(
                            af[i], bfr[g], acc[i][g], 0, 0, 0);
            }
            __syncthreads();
        }
    }

    const int jlo = lane & 15;
    const int j = jg * 16 + jlo;
    float bs[4], vv[4];
#pragma unroll
    for (int g = 0; g < 4; ++g) {
        const int col = jg * 64 + g * 16 + jlo;
        bs[g] = bias_p[col];
        vv[g] = ENC ? 0.f : v_p[col];
    }
#pragma unroll
    for (int i = 0; i < 4; ++i) {
#pragma unroll
        for (int r = 0; r < 4; ++r) {
            const int row = bm + wid * 64 + i * 16 + (lane >> 4) * 4 + r;
            float gi = acc[i][0][r] + bs[0];
            float gf = acc[i][1][r] + bs[1];
            float gg = acc[i][2][r] + bs[2];
            float go = acc[i][3][r] + bs[3];
            if constexpr (!ENC) {
                const float uy = u[row];
                gi += uy * vv[0]; gf += uy * vv[1];
                gg += uy * vv[2]; go += uy * vv[3];
            }
            const size_t idx = (size_t)row * 1024 + j;
            const float cn = sg(gf) * c[idx] + sg(gi) * tf(gg);
            const float hn = sg(go) * tf(cn);
            c[idx] = cn;
            h_bf_out[idx] = f2bf(hn);
            if constexpr (ENC) {
                xenc[(((size_t)row * T_ + t) << 10) + j] = f2bf(hn);
            } else {
                h[idx] = hn;
                c_bf[idx] = f2bf(cn);
            }
        }
    }
}

// ===========================================================================
// Prep kernels
// ===========================================================================
__global__ __launch_bounds__(256) void attn_prep(
    const float* __restrict__ X, const float* __restrict__ eaw, float* __restrict__ alpha)
{
    const int b = blockIdx.x, tid = threadIdx.x;
    __shared__ float wx[T_];
    __shared__ float red[4];
    if (tid < T_) wx[tid] = eaw[2 * H_ + tid];
    __syncthreads();
    const float* xb = X + (size_t)b * T_ * I_;
    float a0 = 0.0f, a1 = 0.0f;
#pragma unroll
    for (int t = 0; t < T_; ++t) {
        a0 = fmaf(xb[t * I_ + tid], wx[t], a0);
        a1 = fmaf(xb[t * I_ + tid + 256], wx[t], a1);
    }
    float m = fmaxf(a0, a1);
#pragma unroll
    for (int off = 32; off; off >>= 1) m = fmaxf(m, __shfl_down(m, off));
    if ((tid & 63) == 0) red[tid >> 6] = m;
    __syncthreads();
    m = fmaxf(fmaxf(red[0], red[1]), fmaxf(red[2], red[3]));
    __syncthreads();
    const float e0 = expf(a0 - m), e1 = expf(a1 - m);
    float ssum = e0 + e1;
#pragma unroll
    for (int off = 32; off; off >>= 1) ssum += __shfl_down(ssum, off);
    if ((tid & 63) == 0) red[tid >> 6] = ssum;
    __syncthreads();
    const float inv = 1.0f / (red[0] + red[1] + red[2] + red[3]);
    alpha[(size_t)b * I_ + tid]       = e0 * inv;
    alpha[(size_t)b * I_ + tid + 256] = e1 * inv;
}

__global__ __launch_bounds__(256) void build_xt(
    const float* __restrict__ X, const float* __restrict__ alpha, u16* __restrict__ Xt)
{
    const int il = blockIdx.x * 256 + threadIdx.x;
    const int t = blockIdx.y;
    const int b = il >> 9, i = il & 511;
    const float val = alpha[il] * X[(((size_t)b * T_ + t) << 9) + i];
    Xt[((size_t)t * B_ + b) * I_ + i] = f2bf(val);
}

// W1 (1024 x 3072) -> W1dc bf16 (1024 x 2048) + W1x bf16 (1024 x 1024)
__global__ __launch_bounds__(256) void split_w1(
    const float* __restrict__ W1, u16* __restrict__ W1dc, u16* __restrict__ W1x)
{
    const int id = blockIdx.x * 256 + threadIdx.x;  // < 1024*768
    const int f = id / 768, c4 = (id % 768) * 4;
    const float4 v = *(const float4*)(W1 + (size_t)f * 3072 + c4);
    ushort4 s; s.x = f2bf(v.x); s.y = f2bf(v.y); s.z = f2bf(v.z); s.w = f2bf(v.w);
    if (c4 < 2048) *(ushort4*)(W1dc + (size_t)f * 2048 + c4) = s;
    else           *(ushort4*)(W1x  + (size_t)f * 1024 + (c4 - 2048)) = s;
}

// gate-interleave permutation: dst row n' <- src row n
__global__ __launch_bounds__(256) void perm_w(
    const float* __restrict__ src, u16* __restrict__ dst, int K)
{
    const int id = blockIdx.x * 256 + threadIdx.x;  // < 4096*(K/4)
    const int K4 = K >> 2;
    const int np = id / K4, c4 = (id % K4) * 4;
    const int gate = (np >> 4) & 3;
    const int j = (np >> 6) * 16 + (np & 15);
    const int n = (gate << 10) + j;
    const float4 v = *(const float4*)(src + (size_t)n * K + c4);
    ushort4 s; s.x = f2bf(v.x); s.y = f2bf(v.y); s.z = f2bf(v.z); s.w = f2bf(v.w);
    *(ushort4*)(dst + (size_t)np * K + c4) = s;
}

__global__ __launch_bounds__(256) void perm_bv(
    const float* __restrict__ b1, const float* __restrict__ b2,
    const float* __restrict__ wv, float* __restrict__ bias_p, float* __restrict__ wv_p)
{
    const int np = blockIdx.x * 256 + threadIdx.x;  // < 4096
    const int gate = (np >> 4) & 3;
    const int j = (np >> 6) * 16 + (np & 15);
    const int n = (gate << 10) + j;
    bias_p[np] = b1[n] + b2[n];
    if (wv) wv_p[np] = wv[n];
}

// ===========================================================================
// Vectorized decoder attention: ushort4/float4 per lane, 2 barriers total.
// ===========================================================================
__global__ __launch_bounds__(256) void dec_attn_v(
    const float* __restrict__ pre, const u16* __restrict__ Xproj,
    const u16* __restrict__ Xenc, const float* __restrict__ W2,
    const float* __restrict__ b2, const float* __restrict__ fc_w,
    const float* __restrict__ fc_b, const float* __restrict__ y_prev,
    int step, float* __restrict__ ctx, float* __restrict__ ytil)
{
    const int b = blockIdx.x, tid = threadIdx.x;
    const int lane = tid & 63, w = tid >> 6;
    const int e4 = tid * 4;
    __shared__ float redw[T_][4];
    __shared__ float red[4];

    const float4 pr  = *(const float4*)(pre + (size_t)b * 1024 + e4);
    const float4 w2r = *(const float4*)(W2 + e4);
    const u16* xp = Xproj + (size_t)b * T_ * 1024;

#pragma unroll
    for (int t = 0; t < T_; ++t) {
        const ushort4 xv = *(const ushort4*)(xp + t * 1024 + e4);
        float s = tf(pr.x + bf2f(xv.x)) * w2r.x;
        s += tf(pr.y + bf2f(xv.y)) * w2r.y;
        s += tf(pr.z + bf2f(xv.z)) * w2r.z;
        s += tf(pr.w + bf2f(xv.w)) * w2r.w;
#pragma unroll
        for (int off = 32; off; off >>= 1) s += __shfl_down(s, off);
        if (lane == 0) redw[t][w] = s;
    }
    __syncthreads();

    // all threads redundantly compute softmax over 32 scores (cheap)
    float sc[T_];
    float mx = -1e30f;
#pragma unroll
    for (int t = 0; t < T_; ++t) {
        sc[t] = redw[t][0] + redw[t][1] + redw[t][2] + redw[t][3] + b2[0];
        mx = fmaxf(mx, sc[t]);
    }
    float ssum = 0.0f;
#pragma unroll
    for (int t = 0; t < T_; ++t) { sc[t] = __expf(sc[t] - mx); ssum += sc[t]; }
    const float inv = 1.0f / ssum;

    const u16* xe = Xenc + (size_t)b * T_ * 1024;
    float cx0 = 0.f, cx1 = 0.f, cx2 = 0.f, cx3 = 0.f;
#pragma unroll
    for (int t = 0; t < T_; ++t) {
        const ushort4 xv = *(const ushort4*)(xe + t * 1024 + e4);
        const float bt = sc[t];
        cx0 = fmaf(bt, bf2f(xv.x), cx0);
        cx1 = fmaf(bt, bf2f(xv.y), cx1);
        cx2 = fmaf(bt, bf2f(xv.z), cx2);
        cx3 = fmaf(bt, bf2f(xv.w), cx3);
    }
    float4 cv; cv.x = cx0 * inv; cv.y = cx1 * inv; cv.z = cx2 * inv; cv.w = cx3 * inv;
    *(float4*)(ctx + (size_t)b * 1024 + e4) = cv;

    const float4 fw = *(const float4*)(fc_w + e4);
    float yt = cv.x * fw.x + cv.y * fw.y + cv.z * fw.z + cv.w * fw.w;
#pragma unroll
    for (int off = 32; off; off >>= 1) yt += __shfl_down(yt, off);
    if (lane == 0) red[w] = yt;
    __syncthreads();
    if (tid == 0)
        ytil[b] = red[0] + red[1] + red[2] + red[3]
                + y_prev[(size_t)b * T_ + step] * fc_w[1024] + fc_b[0];
}

__global__ __launch_bounds__(256) void final_out(
    const float* __restrict__ d, const float* __restrict__ ctx,
    const float* __restrict__ ffw, const float* __restrict__ ffb,
    float* __restrict__ out)
{
    const int b = blockIdx.x, tid = threadIdx.x;
    float s = 0.0f;
#pragma unroll
    for (int q = 0; q < 4; ++q) {
        const int e = tid + 256 * q;
        s += d[(size_t)b * 1024 + e] * ffw[e] + ctx[(size_t)b * 1024 + e] * ffw[1024 + e];
    }
#pragma unroll
    for (int off = 32; off; off >>= 1) s += __shfl_down(s, off);
    __shared__ float red[4];
    if ((tid & 63) == 0) red[tid >> 6] = s;
    __syncthreads();
    if (tid == 0) out[b] = red[0] + red[1] + red[2] + red[3] + ffb[0];
}

// ===========================================================================
// Fallback fp32-VALU path (R3, proven)
// ===========================================================================
template <int BM, int BN, int BK, int TM, int TN, typename TA, typename TC>
__global__ __launch_bounds__(256) void gemm(
    int M, int N,
    const TA* __restrict__ A1, int lda1, const float* __restrict__ B1, int ldb1, int K1,
    const TA* __restrict__ A2, int lda2, const float* __restrict__ B2, int ldb2, int K2,
    const float* __restrict__ ascale, int ldsc,
    const float* __restrict__ bias1, const float* __restrict__ bias2,
    const float* __restrict__ u, const float* __restrict__ v,
    TC* __restrict__ C, int ldc)
{
    constexpr int TCOLS = BN / TN;
    constexpr int KCH = BK / 4;
    constexpr int ROWS_PER_PASS = 256 / KCH;

    __shared__ float As[BK][BM + 4];
    __shared__ float Bs[BK][BN + 4];

    const int tid = threadIdx.x;
    const int tn = tid % TCOLS;
    const int tm = tid / TCOLS;
    const int bn = blockIdx.x * BN;
    const int bm = blockIdx.y * BM;
    const int lrow = tid / KCH;
    const int lkc  = (tid % KCH) * 4;

    float acc[TM][TN];
#pragma unroll
    for (int i = 0; i < TM; ++i)
#pragma unroll
        for (int j = 0; j < TN; ++j) acc[i][j] = 0.0f;

    for (int pair = 0; pair < 2; ++pair) {
        const TA* A  = pair ? A2 : A1;
        const float* Bp = pair ? B2 : B1;
        const float* sc = pair ? nullptr : ascale;
        const int lda = pair ? lda2 : lda1;
        const int ldb = pair ? ldb2 : ldb1;
        const int K   = pair ? K2 : K1;
        if (K == 0) continue;
        for (int k0 = 0; k0 < K; k0 += BK) {
            __syncthreads();
#pragma unroll
            for (int r = 0; r < BM; r += ROWS_PER_PASS) {
                const int row = bm + r + lrow;
                float4 val = ld4(A + (size_t)row * lda + (k0 + lkc));
                if (sc) {
                    const float4 s = *(const float4*)(sc + (size_t)row * ldsc + (k0 + lkc));
                    val.x *= s.x; val.y *= s.y; val.z *= s.z; val.w *= s.w;
                }
                As[lkc + 0][r + lrow] = val.x;
                As[lkc + 1][r + lrow] = val.y;
                As[lkc + 2][r + lrow] = val.z;
                As[lkc + 3][r + lrow] = val.w;
            }
#pragma unroll
            for (int r = 0; r < BN; r += ROWS_PER_PASS) {
                const float4 val = *(const float4*)(Bp + (size_t)(bn + r + lrow) * ldb + (k0 + lkc));
                Bs[lkc + 0][r + lrow] = val.x;
                Bs[lkc + 1][r + lrow] = val.y;
                Bs[lkc + 2][r + lrow] = val.z;
                Bs[lkc + 3][r + lrow] = val.w;
            }
            __syncthreads();
#pragma unroll
            for (int k = 0; k < BK; ++k) {
                float a[TM], bv[TN];
#pragma unroll
                for (int i = 0; i < TM; ++i) a[i] = As[k][tm * TM + i];
#pragma unroll
                for (int j = 0; j < TN; ++j) bv[j] = Bs[k][tn * TN + j];
#pragma unroll
                for (int i = 0; i < TM; ++i)
#pragma unroll
                    for (int j = 0; j < TN; ++j)
                        acc[i][j] = fmaf(a[i], bv[j], acc[i][j]);
            }
        }
    }

#pragma unroll
    for (int i = 0; i < TM; ++i) {
        const int m = bm + tm * TM + i;
        const float um = u ? u[m] : 0.0f;
#pragma unroll
        for (int j = 0; j < TN; j += 4) {
            const int n = bn + tn * TN + j;
            float r[4];
#pragma unroll
            for (int q = 0; q < 4; ++q) {
                float val = acc[i][j + q];
                if (bias1) val += bias1[n + q];
                if (bias2) val += bias2[n + q];
                if (u)     val += um * v[n + q];
                r[q] = val;
            }
            if constexpr (sizeof(TC) == 4) {
                float4 f; f.x = r[0]; f.y = r[1]; f.z = r[2]; f.w = r[3];
                *(float4*)((float*)C + (size_t)m * ldc + n) = f;
            } else {
                ushort4 s;
                s.x = f2bf(r[0]); s.y = f2bf(r[1]); s.z = f2bf(r[2]); s.w = f2bf(r[3]);
                *(ushort4*)((u16*)C + (size_t)m * ldc + n) = s;
            }
        }
    }
}

template <typename TX>
__global__ __launch_bounds__(256) void lstm_pw(
    const float* __restrict__ gates, float* __restrict__ h, float* __restrict__ c,
    TX* __restrict__ xenc, int t)
{
    const size_t idx = (size_t)blockIdx.x * 256 + threadIdx.x;
    const int b = (int)(idx >> 10);
    const int j = (int)(idx & 1023);
    const float* g = gates + ((size_t)b << 12);
    const float gi = g[j], gf = g[j + 1024], gg = g[j + 2048], go = g[j + 3072];
    const float si = 1.0f / (1.0f + expf(-gi));
    const float sf = 1.0f / (1.0f + expf(-gf));
    const float so = 1.0f / (1.0f + expf(-go));
    const float cn = sf * c[idx] + si * tanhf(gg);
    const float hn = so * tanhf(cn);
    c[idx] = cn;
    h[idx] = hn;
    if (xenc) {
        if constexpr (sizeof(TX) == 4) ((float*)xenc)[(((size_t)b * T_ + t) << 10) + j] = hn;
        else ((u16*)xenc)[(((size_t)b * T_ + t) << 10) + j] = f2bf(hn);
    }
}

template <typename TX>
__global__ __launch_bounds__(256) void dec_attn(
    const float* __restrict__ pre, const TX* __restrict__ Xproj,
    const TX* __restrict__ Xenc, const float* __restrict__ W2,
    const float* __restrict__ b2, const float* __restrict__ fc_w,
    const float* __restrict__ fc_b, const float* __restrict__ y_prev,
    int step, float* __restrict__ ctx, float* __restrict__ ytil)
{
    const int b = blockIdx.x, tid = threadIdx.x;
    __shared__ float red[4];
    __shared__ float sc[T_];
    float pr[4], w2r[4];
#pragma unroll
    for (int q = 0; q < 4; ++q) {
        pr[q]  = pre[(size_t)b * 1024 + tid + 256 * q];
        w2r[q] = W2[tid + 256 * q];
    }
    const TX* xp = Xproj + (size_t)b * T_ * 1024;
    for (int t = 0; t < T_; ++t) {
        float s = 0.0f;
#pragma unroll
        for (int q = 0; q < 4; ++q)
            s += tanhf(pr[q] + ld1(xp + t * 1024 + tid + 256 * q)) * w2r[q];
#pragma unroll
        for (int off = 32; off; off >>= 1) s += __shfl_down(s, off);
        if ((tid & 63) == 0) red[tid >> 6] = s;
        __syncthreads();
        if (tid == 0) sc[t] = red[0] + red[1] + red[2] + red[3] + b2[0];
        __syncthreads();
    }
    float mx = -1e30f;
#pragma unroll
    for (int t = 0; t < T_; ++t) mx = fmaxf(mx, sc[t]);
    float beta[T_];
    float ssum = 0.0f;
#pragma unroll
    for (int t = 0; t < T_; ++t) { beta[t] = expf(sc[t] - mx); ssum += beta[t]; }
    const float inv = 1.0f / ssum;
    const TX* xe = Xenc + (size_t)b * T_ * 1024;
    float cx[4] = {0.0f, 0.0f, 0.0f, 0.0f};
    for (int t = 0; t < T_; ++t) {
        const float bt = beta[t];
#pragma unroll
        for (int q = 0; q < 4; ++q)
            cx[q] = fmaf(bt, ld1(xe + t * 1024 + tid + 256 * q), cx[q]);
    }
    float yt = 0.0f;
#pragma unroll
    for (int q = 0; q < 4; ++q) {
        const float cv = cx[q] * inv;
        ctx[(size_t)b * 1024 + tid + 256 * q] = cv;
        yt += cv * fc_w[tid + 256 * q];
    }
#pragma unroll
    for (int off = 32; off; off >>= 1) yt += __shfl_down(yt, off);
    if ((tid & 63) == 0) red[tid >> 6] = yt;
    __syncthreads();
    if (tid == 0)
        ytil[b] = red[0] + red[1] + red[2] + red[3]
                + y_prev[(size_t)b * T_ + step] * fc_w[1024] + fc_b[0];
}

// ===========================================================================
static void run_mfma(void* const* d_in, float* out, char* ws, hipStream_t stream)
{
    const float* X      = (const float*)d_in[0];
    const float* y_prev = (const float*)d_in[1];
    const float* eaw    = (const float*)d_in[2];
    const float* Wih_e  = (const float*)d_in[4];
    const float* Whh_e  = (const float*)d_in[5];
    const float* bih_e  = (const float*)d_in[6];
    const float* bhh_e  = (const float*)d_in[7];
    const float* W1     = (const float*)d_in[8];
    const float* b1     = (const float*)d_in[9];
    const float* W2     = (const float*)d_in[10];
    const float* b2     = (const float*)d_in[11];
    const float* Wih_d  = (const float*)d_in[12];
    const float* Whh_d  = (const float*)d_in[13];
    const float* bih_d  = (const float*)d_in[14];
    const float* bhh_d  = (const float*)d_in[15];
    const float* fc_w   = (const float*)d_in[16];
    const float* fc_b   = (const float*)d_in[17];
    const float* ff_w   = (const float*)d_in[18];
    const float* ff_b   = (const float*)d_in[19];

    auto au = [](size_t x) { return (x + 255) & ~(size_t)255; };
    char* p = ws;
    u16* Xenc   = (u16*)p;    p += au((size_t)B_ * T_ * H_ * 2);   // 134 MB
    u16* Xt     = (u16*)p;                                         // union:
    u16* Xproj  = (u16*)p;    p += au((size_t)B_ * T_ * H_ * 2);   // 134 MB
    float* h    = (float*)p;  p += au((size_t)B_ * H_ * 4);        // decoder d
    float* c    = (float*)p;  p += au((size_t)B_ * H_ * 4);
    u16* hbf0   = (u16*)p;    p += au((size_t)B_ * H_ * 2);
    u16* hbf1   = (u16*)p;    p += au((size_t)B_ * H_ * 2);
    u16* c_bf   = (u16*)p;    p += au((size_t)B_ * H_ * 2);
    float* pre  = (float*)p;  p += au((size_t)B_ * E_ * 4);
    float* ctx  = (float*)p;  p += au((size_t)B_ * E_ * 4);
    u16* Wih_e_p = (u16*)p;   p += au((size_t)G_ * I_ * 2);
    u16* Whh_e_p = (u16*)p;   p += au((size_t)G_ * H_ * 2);
    u16* Whh_d_p = (u16*)p;   p += au((size_t)G_ * H_ * 2);
    u16* W1dc_bf = (u16*)p;   p += au((size_t)E_ * 2048 * 2);
    u16* W1x_bf  = (u16*)p;   p += au((size_t)E_ * 1024 * 2);
    float* bias_e_p = (float*)p; p += au((size_t)G_ * 4);
    float* bias_d_p = (float*)p; p += au((size_t)G_ * 4);
    float* wv_p     = (float*)p; p += au((size_t)G_ * 4);
    float* alpha    = (float*)p; p += au((size_t)B_ * I_ * 4);
    float* ytil     = (float*)p;

    // weight prep (permuted gates layout)
    perm_w<<<(G_ * (I_ / 4)) / 256, 256, 0, stream>>>(Wih_e, Wih_e_p, I_);
    perm_w<<<(G_ * (H_ / 4)) / 256, 256, 0, stream>>>(Whh_e, Whh_e_p, H_);
    perm_w<<<(G_ * (H_ / 4)) / 256, 256, 0, stream>>>(Whh_d, Whh_d_p, H_);
    perm_bv<<<G_ / 256, 256, 0, stream>>>(bih_e, bhh_e, nullptr, bias_e_p, nullptr);
    perm_bv<<<G_ / 256, 256, 0, stream>>>(bih_d, bhh_d, Wih_d, bias_d_p, wv_p);
    split_w1<<<(E_ * 768) / 256, 256, 0, stream>>>(W1, W1dc_bf, W1x_bf);

    hipMemsetAsync(c, 0, (size_t)B_ * H_ * 4, stream);
    hipMemsetAsync(hbf0, 0, (size_t)B_ * H_ * 2, stream);

    attn_prep<<<B_, 256, 0, stream>>>(X, eaw, alpha);
    build_xt<<<dim3(B_ * I_ / 256, T_), 256, 0, stream>>>(X, alpha, Xt);

    // ---- encoder: fused gates-GEMM + LSTM (h_bf double-buffered)
    for (int t = 0; t < T_; ++t) {
        u16* hin  = (t & 1) ? hbf1 : hbf0;
        u16* hout = (t & 1) ? hbf0 : hbf1;
        gemm_lstm<true><<<dim3(H_ / 16, B_ / 256), 256, 0, stream>>>(
            Xt + (size_t)t * B_ * I_, I_, Wih_e_p, I_,
            hin, H_, Whh_e_p, H_,
            bias_e_p, nullptr, nullptr,
            c, nullptr, hout, nullptr, Xenc, t);
    }

    // ---- Xproj = Xenc @ W1x^T + b1 (overwrites Xt union; Xt dead)
    gemm_bf16<128, 128, u16><<<dim3(E_ / 128, (B_ * T_) / 128), 256, 0, stream>>>(
        Xenc, H_, W1x_bf, H_, H_,
        nullptr, 0, nullptr, 0, 0,
        b1, nullptr, nullptr, nullptr, Xproj, E_);

    // ---- decoder
    hipMemsetAsync(c, 0, (size_t)B_ * H_ * 4, stream);
    hipMemsetAsync(hbf0, 0, (size_t)B_ * H_ * 2, stream);
    hipMemsetAsync(c_bf, 0, (size_t)B_ * H_ * 2, stream);

    for (int t = 0; t < T_; ++t) {
        u16* hin  = (t & 1) ? hbf1 : hbf0;
        u16* hout = (t & 1) ? hbf0 : hbf1;
        // pre = d @ W1[:, :1024]^T + c @ W1[:, 1024:2048]^T
        gemm_bf16<128, 64, float><<<dim3(E_ / 64, B_ / 128), 256, 0, stream>>>(
            hin, H_, W1dc_bf, 2048, H_,
            c_bf, H_, W1dc_bf + 1024, 2048, H_,
            nullptr, nullptr, nullptr, nullptr, pre, E_);
        dec_attn_v<<<B_, 256, 0, stream>>>(pre, Xproj, Xenc, W2, b2, fc_w, fc_b,
                                           y_prev, t, ctx, ytil);
        gemm_lstm<false><<<dim3(H_ / 16, B_ / 256), 256, 0, stream>>>(
            hin, H_, Whh_d_p, H_,
            (const u16*)nullptr, 0, nullptr, 0,
            bias_d_p, ytil, wv_p,
            c, h, hout, c_bf, nullptr, t);
    }

    final_out<<<B_, 256, 0, stream>>>(h, ctx, ff_w, ff_b, out);
}

// ---- R3 lean fallback ------------------------------------------------------
static void run_fallback(void* const* d_in, float* out, char* ws, hipStream_t stream)
{
    const float* X      = (const float*)d_in[0];
    const float* y_prev = (const float*)d_in[1];
    const float* eaw    = (const float*)d_in[2];
    const float* Wih_e  = (const float*)d_in[4];
    const float* Whh_e  = (const float*)d_in[5];
    const float* bih_e  = (const float*)d_in[6];
    const float* bhh_e  = (const float*)d_in[7];
    const float* W1     = (const float*)d_in[8];
    const float* b1     = (const float*)d_in[9];
    const float* W2     = (const float*)d_in[10];
    const float* b2     = (const float*)d_in[11];
    const float* Wih_d  = (const float*)d_in[12];
    const float* Whh_d  = (const float*)d_in[13];
    const float* bih_d  = (const float*)d_in[14];
    const float* bhh_d  = (const float*)d_in[15];
    const float* fc_w   = (const float*)d_in[16];
    const float* fc_b   = (const float*)d_in[17];
    const float* ff_w   = (const float*)d_in[18];
    const float* ff_b   = (const float*)d_in[19];

    auto au = [](size_t x) { return (x + 255) & ~(size_t)255; };
    char* p = ws;
    float* alpha = (float*)p;  p += au((size_t)B_ * I_ * 4);
    u16*   Xenc  = (u16*)p;    p += au((size_t)B_ * T_ * H_ * 2);
    u16*   Xproj = (u16*)p;    p += au((size_t)B_ * T_ * H_ * 2);
    float* gates = (float*)p;  p += au((size_t)B_ * G_ * 4);
    float* h     = (float*)p;  p += au((size_t)B_ * H_ * 4);
    float* c     = (float*)p;  p += au((size_t)B_ * H_ * 4);
    float* pre   = (float*)p;  p += au((size_t)B_ * E_ * 4);
    float* ctx   = (float*)p;  p += au((size_t)B_ * E_ * 4);
    float* ytil  = (float*)p;

    hipMemsetAsync(h, 0, (size_t)B_ * H_ * 4, stream);
    hipMemsetAsync(c, 0, (size_t)B_ * H_ * 4, stream);

    attn_prep<<<B_, 256, 0, stream>>>(X, eaw, alpha);

    for (int t = 0; t < T_; ++t) {
        gemm<128, 128, 16, 8, 8, float, float><<<dim3(G_ / 128, B_ / 128), 256, 0, stream>>>(
            B_, G_,
            X + (size_t)t * I_, T_ * I_, Wih_e, I_, I_,
            h, H_, Whh_e, H_, H_,
            alpha, I_,
            bih_e, bhh_e, nullptr, nullptr, gates, G_);
        lstm_pw<u16><<<(B_ * H_) / 256, 256, 0, stream>>>(gates, h, c, Xenc, t);
    }

    gemm<128, 128, 16, 8, 8, u16, u16><<<dim3(E_ / 128, (B_ * T_) / 128), 256, 0, stream>>>(
        B_ * T_, E_,
        Xenc, H_, W1 + 2048, 3072, H_,
        (const u16*)nullptr, 0, nullptr, 0, 0,
        nullptr, 0,
        b1, nullptr, nullptr, nullptr, Xproj, E_);

    hipMemsetAsync(h, 0, (size_t)B_ * H_ * 4, stream);
    hipMemsetAsync(c, 0, (size_t)B_ * H_ * 4, stream);

    for (int t = 0; t < T_; ++t) {
        gemm<64, 64, 16, 4, 4, float, float><<<dim3(E_ / 64, B_ / 64), 256, 0, stream>>>(
            B_, E_,
            h, H_, W1, 3072, H_,
            c, H_, W1 + 1024, 3072, H_,
            nullptr, 0,
            nullptr, nullptr, nullptr, nullptr, pre, E_);
        dec_attn<u16><<<B_, 256, 0, stream>>>(pre, Xproj, Xenc, W2, b2, fc_w, fc_b,
                                              y_prev, t, ctx, ytil);
        gemm<128, 128, 16, 8, 8, float, float><<<dim3(G_ / 128, B_ / 128), 256, 0, stream>>>(
            B_, G_,
            h, H_, Whh_d, H_, H_,
            (const float*)nullptr, 0, nullptr, 0, 0,
            nullptr, 0,
            bih_d, bhh_d, ytil, Wih_d, gates, G_);
        lstm_pw<float><<<(B_ * H_) / 256, 256, 0, stream>>>(gates, h, c, nullptr, t);
    }

    final_out<<<B_, 256, 0, stream>>>(h, ctx, ff_w, ff_b, out);
}

extern "C" void kernel_launch(void* const* d_in, const int* in_sizes, int n_in,
                              void* d_out, int out_size, void* d_ws, size_t ws_size,
                              hipStream_t stream)
{
    auto au = [](size_t x) { return (x + 255) & ~(size_t)255; };
    const size_t needM =
        2 * au((size_t)B_ * T_ * H_ * 2) +           // Xenc + (Xt|Xproj union)
        2 * au((size_t)B_ * H_ * 4) +                // h, c
        3 * au((size_t)B_ * H_ * 2) +                // hbf0, hbf1, c_bf
        2 * au((size_t)B_ * E_ * 4) +                // pre, ctx
        au((size_t)G_ * I_ * 2) + 2 * au((size_t)G_ * H_ * 2) +
        au((size_t)E_ * 2048 * 2) + au((size_t)E_ * 1024 * 2) +
        3 * au((size_t)G_ * 4) +                     // bias_e_p, bias_d_p, wv_p
        au((size_t)B_ * I_ * 4) +                    // alpha
        au((size_t)B_ * 4) + 4096;                   // ytil + slack

    if (ws_size >= needM)
        run_mfma(d_in, (float*)d_out, (char*)d_ws, stream);
    else
        run_fallback(d_in, (float*)d_out, (char*)d_ws, stream);
}

// Round 7
// 6206.989 us; speedup vs baseline: 4.7131x; 1.0692x over previous
//
#include <hip/hip_runtime.h>
#include <cstddef>
#include <cstdint>

// DA-RNN for MI355X — round 7 (resubmit of R6: broker timeout, changes
// untested). R6 changes: occupancy fix for pre-GEMM (64x64 tile), dec_attn
// 16B loads (ushort8, 2-half), fused attn_prep+Xt build, t=0 dead-GEMM
// elision. R5 baseline: 6.64 ms; Xproj gemm 190us @ 29% MfmaUtil, 0 bank
// conflicts; every per-step kernel < 190 us.
// B=2048, T=32, I=512, H=D=E=1024, 4H=4096.

#define B_ 2048
#define T_ 32
#define I_ 512
#define H_ 1024
#define G_ 4096  // 4*H
#define E_ 1024

typedef unsigned short u16;
typedef float f32x4 __attribute__((ext_vector_type(4)));
typedef short bf16x8 __attribute__((ext_vector_type(8)));
typedef unsigned short us8 __attribute__((ext_vector_type(8)));
typedef __attribute__((address_space(1))) const void gv_t;
typedef __attribute__((address_space(3))) void lv_t;

// ---- bf16 helpers ----------------------------------------------------------
__device__ __forceinline__ float bf2f(u16 u) {
    union { float f; unsigned v; } w; w.v = ((unsigned)u) << 16; return w.f;
}
__device__ __forceinline__ u16 f2bf(float f) {
    union { float f; unsigned v; } w; w.f = f;
    unsigned r = w.v + 0x7fff + ((w.v >> 16) & 1);
    return (u16)(r >> 16);
}
template <typename T>
__device__ __forceinline__ float ld1(const T* p) {
    if constexpr (sizeof(T) == 4) return *(const float*)p;
    else return bf2f(*(const u16*)p);
}
template <typename T>
__device__ __forceinline__ float4 ld4(const T* p) {
    if constexpr (sizeof(T) == 4) {
        return *(const float4*)p;
    } else {
        const ushort4 u = *(const ushort4*)p;
        float4 r; r.x = bf2f(u.x); r.y = bf2f(u.y); r.z = bf2f(u.z); r.w = bf2f(u.w);
        return r;
    }
}
__device__ __forceinline__ float tf(float x) {        // tanh via hw exp
    const float e = __expf(2.0f * x);
    return 1.0f - 2.0f / (e + 1.0f);
}
__device__ __forceinline__ float sg(float x) {        // sigmoid
    return 1.0f / (1.0f + __expf(-x));
}

// ---- LDS swizzle (T2, proven conflict-free R4/R5) --------------------------
__device__ __forceinline__ int lds_off(int row, int k) {  // k: elem in [0,64)
    return row * 128 + ((k * 2) ^ ((row & 7) << 4));
}

template <int ROWS>
__device__ __forceinline__ void stage_tile(char* lds, const u16* g,
                                           int row0, int ld, int k0, int tid)
{
    const int rb = tid >> 3, slot = tid & 7;
#pragma unroll
    for (int i = 0; i < ROWS / 32; ++i) {
        const int r = i * 32 + rb;
        const int ss = slot ^ (r & 7);             // inverse-swizzled source
        const u16* src = g + (size_t)(row0 + r) * ld + k0 + ss * 8;
        char* dst = lds + i * 4096 + (tid & 192) * 16;  // wave-uniform base
        __builtin_amdgcn_global_load_lds((gv_t*)src, (lv_t*)dst, 16, 0, 0);
    }
}

// ===========================================================================
// Plain MFMA GEMM: C = A1@B1^T + A2@B2^T + bias1 (+bias2 + u*v)
// ===========================================================================
template <int BM, int BN, typename TC>
__global__ __launch_bounds__(256) void gemm_bf16(
    const u16* __restrict__ A1, int lda1, const u16* __restrict__ B1, int ldb1, int K1,
    const u16* __restrict__ A2, int lda2, const u16* __restrict__ B2, int ldb2, int K2,
    const float* __restrict__ bias1, const float* __restrict__ bias2,
    const float* __restrict__ u, const float* __restrict__ v,
    TC* __restrict__ C, int ldc)
{
    constexpr int FM = BM / 32, FN = BN / 32;
    __shared__ __align__(16) char lds[(BM + BN) * 128];
    char* ldsA = lds;
    char* ldsB = lds + BM * 128;
    const int tid = threadIdx.x;
    const int lane = tid & 63, wid = tid >> 6;
    const int wm = wid >> 1, wn = wid & 1;
    const int bm = blockIdx.y * BM, bn = blockIdx.x * BN;

    f32x4 acc[FM][FN] = {};

    for (int pair = 0; pair < 2; ++pair) {
        const u16* A = pair ? A2 : A1;
        const u16* Bw = pair ? B2 : B1;
        const int lda = pair ? lda2 : lda1;
        const int ldb = pair ? ldb2 : ldb1;
        const int K = pair ? K2 : K1;
        if (K == 0) continue;
        for (int k0 = 0; k0 < K; k0 += 64) {
            stage_tile<BM>(ldsA, A, bm, lda, k0, tid);
            stage_tile<BN>(ldsB, Bw, bn, ldb, k0, tid);
            __syncthreads();
#pragma unroll
            for (int kk = 0; kk < 64; kk += 32) {
                const int krd = kk + (lane >> 4) * 8;
                bf16x8 af[FM], bfr[FN];
#pragma unroll
                for (int i = 0; i < FM; ++i)
                    af[i] = *(const bf16x8*)(ldsA +
                        lds_off(wm * FM * 16 + i * 16 + (lane & 15), krd));
#pragma unroll
                for (int j = 0; j < FN; ++j)
                    bfr[j] = *(const bf16x8*)(ldsB +
                        lds_off(wn * FN * 16 + j * 16 + (lane & 15), krd));
#pragma unroll
                for (int i = 0; i < FM; ++i)
#pragma unroll
                    for (int j = 0; j < FN; ++j)
                        acc[i][j] = __builtin_amdgcn_mfma_f32_16x16x32_bf16(
                            af[i], bfr[j], acc[i][j], 0, 0, 0);
            }
            __syncthreads();
        }
    }

#pragma unroll
    for (int j = 0; j < FN; ++j) {
        const int col = bn + wn * FN * 16 + j * 16 + (lane & 15);
        const float bsum = (bias1 ? bias1[col] : 0.f) + (bias2 ? bias2[col] : 0.f);
        const float vv = v ? v[col] : 0.f;
#pragma unroll
        for (int i = 0; i < FM; ++i) {
#pragma unroll
            for (int r = 0; r < 4; ++r) {
                const int row = bm + wm * FM * 16 + i * 16 + (lane >> 4) * 4 + r;
                float val = acc[i][j][r] + bsum;
                if (u) val += u[row] * vv;
                if constexpr (sizeof(TC) == 4)
                    ((float*)C)[(size_t)row * ldc + col] = val;
                else
                    ((u16*)C)[(size_t)row * ldc + col] = f2bf(val);
            }
        }
    }
}

// ===========================================================================
// Fused gates-GEMM + LSTM (gate-interleaved weights; see R5 comment).
// h fp32 written only when h != nullptr (last decoder step).
// ===========================================================================
template <bool ENC>
__global__ __launch_bounds__(256) void gemm_lstm(
    const u16* __restrict__ A1, int lda1, const u16* __restrict__ B1, int K1,
    const u16* __restrict__ A2, int lda2, const u16* __restrict__ B2, int K2,
    const float* __restrict__ bias_p, const float* __restrict__ u,
    const float* __restrict__ v_p,
    float* __restrict__ c, float* __restrict__ h,
    u16* __restrict__ h_bf_out, u16* __restrict__ c_bf,
    u16* __restrict__ xenc, int t)
{
    __shared__ __align__(16) char lds[(256 + 64) * 128];
    char* ldsA = lds;
    char* ldsB = lds + 256 * 128;
    const int tid = threadIdx.x, lane = tid & 63, wid = tid >> 6;
    const int bm = blockIdx.y * 256, jg = blockIdx.x;

    f32x4 acc[4][4] = {};

    for (int pair = 0; pair < 2; ++pair) {
        const u16* A = pair ? A2 : A1;
        const u16* Bw = pair ? B2 : B1;
        const int lda = pair ? lda2 : lda1;
        const int K = pair ? K2 : K1;
        if (K == 0) continue;
        for (int k0 = 0; k0 < K; k0 += 64) {
            stage_tile<256>(ldsA, A, bm, lda, k0, tid);
            stage_tile<64>(ldsB, Bw, jg * 64, K, k0, tid);
            __syncthreads();
#pragma unroll
            for (int kk = 0; kk < 64; kk += 32) {
                const int krd = kk + (lane >> 4) * 8;
                bf16x8 af[4], bfr[4];
#pragma unroll
                for (int i = 0; i < 4; ++i)
                    af[i] = *(const bf16x8*)(ldsA +
                        lds_off(wid * 64 + i * 16 + (lane & 15), krd));
#pragma unroll
                for (int g = 0; g < 4; ++g)
                    bfr[g] = *(const bf16x8*)(ldsB +
                        lds_off(g * 16 + (lane & 15), krd));
#pragma unroll
                for (int i = 0; i < 4; ++i)
#pragma unroll
                    for (int g = 0; g < 4; ++g)
                        acc[i][g] = __builtin_amdgcn_mfma_f32_16x16x32_bf16(
                            af[i], bfr[g], acc[i][g], 0, 0, 0);
            }
            __syncthreads();
        }
    }

    const int jlo = lane & 15;
    const int j = jg * 16 + jlo;
    float bs[4], vv[4];
#pragma unroll
    for (int g = 0; g < 4; ++g) {
        const int col = jg * 64 + g * 16 + jlo;
        bs[g] = bias_p[col];
        vv[g] = ENC ? 0.f : v_p[col];
    }
#pragma unroll
    for (int i = 0; i < 4; ++i) {
#pragma unroll
        for (int r = 0; r < 4; ++r) {
            const int row = bm + wid * 64 + i * 16 + (lane >> 4) * 4 + r;
            float gi = acc[i][0][r] + bs[0];
            float gf = acc[i][1][r] + bs[1];
            float gg = acc[i][2][r] + bs[2];
            float go = acc[i][3][r] + bs[3];
            if constexpr (!ENC) {
                const float uy = u[row];
                gi += uy * vv[0]; gf += uy * vv[1];
                gg += uy * vv[2]; go += uy * vv[3];
            }
            const size_t idx = (size_t)row * 1024 + j;
            const float cn = sg(gf) * c[idx] + sg(gi) * tf(gg);
            const float hn = sg(go) * tf(cn);
            c[idx] = cn;
            h_bf_out[idx] = f2bf(hn);
            if constexpr (ENC) {
                xenc[(((size_t)row * T_ + t) << 10) + j] = f2bf(hn);
            } else {
                if (h) h[idx] = hn;
                c_bf[idx] = f2bf(cn);
            }
        }
    }
}

// ===========================================================================
// Fused encoder input attention + X_tilde build (X read once, kept in regs).
// ===========================================================================
__global__ __launch_bounds__(256) void attn_prep_xt(
    const float* __restrict__ X, const float* __restrict__ eaw, u16* __restrict__ Xt)
{
    const int b = blockIdx.x, tid = threadIdx.x;
    __shared__ float wx[T_];
    __shared__ float red[4];
    if (tid < T_) wx[tid] = eaw[2 * H_ + tid];
    __syncthreads();
    const float* xb = X + (size_t)b * T_ * I_;
    float xv0[T_], xv1[T_];
    float a0 = 0.0f, a1 = 0.0f;
#pragma unroll
    for (int t = 0; t < T_; ++t) {
        xv0[t] = xb[t * I_ + tid];
        xv1[t] = xb[t * I_ + tid + 256];
        a0 = fmaf(xv0[t], wx[t], a0);
        a1 = fmaf(xv1[t], wx[t], a1);
    }
    float m = fmaxf(a0, a1);
#pragma unroll
    for (int off = 32; off; off >>= 1) m = fmaxf(m, __shfl_down(m, off));
    if ((tid & 63) == 0) red[tid >> 6] = m;
    __syncthreads();
    m = fmaxf(fmaxf(red[0], red[1]), fmaxf(red[2], red[3]));
    __syncthreads();
    const float e0 = expf(a0 - m), e1 = expf(a1 - m);
    float ssum = e0 + e1;
#pragma unroll
    for (int off = 32; off; off >>= 1) ssum += __shfl_down(ssum, off);
    if ((tid & 63) == 0) red[tid >> 6] = ssum;
    __syncthreads();
    const float inv = 1.0f / (red[0] + red[1] + red[2] + red[3]);
    const float al0 = e0 * inv, al1 = e1 * inv;
#pragma unroll
    for (int t = 0; t < T_; ++t) {
        u16* dst = Xt + ((size_t)t * B_ + b) * I_;
        dst[tid]       = f2bf(al0 * xv0[t]);
        dst[tid + 256] = f2bf(al1 * xv1[t]);
    }
}

// W1 (1024 x 3072) -> W1dc bf16 (1024 x 2048) + W1x bf16 (1024 x 1024)
__global__ __launch_bounds__(256) void split_w1(
    const float* __restrict__ W1, u16* __restrict__ W1dc, u16* __restrict__ W1x)
{
    const int id = blockIdx.x * 256 + threadIdx.x;  // < 1024*768
    const int f = id / 768, c4 = (id % 768) * 4;
    const float4 v = *(const float4*)(W1 + (size_t)f * 3072 + c4);
    ushort4 s; s.x = f2bf(v.x); s.y = f2bf(v.y); s.z = f2bf(v.z); s.w = f2bf(v.w);
    if (c4 < 2048) *(ushort4*)(W1dc + (size_t)f * 2048 + c4) = s;
    else           *(ushort4*)(W1x  + (size_t)f * 1024 + (c4 - 2048)) = s;
}

// gate-interleave permutation: dst row n' <- src row n
__global__ __launch_bounds__(256) void perm_w(
    const float* __restrict__ src, u16* __restrict__ dst, int K)
{
    const int id = blockIdx.x * 256 + threadIdx.x;  // < 4096*(K/4)
    const int K4 = K >> 2;
    const int np = id / K4, c4 = (id % K4) * 4;
    const int gate = (np >> 4) & 3;
    const int j = (np >> 6) * 16 + (np & 15);
    const int n = (gate << 10) + j;
    const float4 v = *(const float4*)(src + (size_t)n * K + c4);
    ushort4 s; s.x = f2bf(v.x); s.y = f2bf(v.y); s.z = f2bf(v.z); s.w = f2bf(v.w);
    *(ushort4*)(dst + (size_t)np * K + c4) = s;
}

__global__ __launch_bounds__(256) void perm_bv(
    const float* __restrict__ b1, const float* __restrict__ b2,
    const float* __restrict__ wv, float* __restrict__ bias_p, float* __restrict__ wv_p)
{
    const int np = blockIdx.x * 256 + threadIdx.x;  // < 4096
    const int gate = (np >> 4) & 3;
    const int j = (np >> 6) * 16 + (np & 15);
    const int n = (gate << 10) + j;
    bias_p[np] = b1[n] + b2[n];
    if (wv) wv_p[np] = wv[n];
}

// ===========================================================================
// Decoder attention v2: ushort8 (16B) loads, 2-half t-split, LDS combine.
// ===========================================================================
__global__ __launch_bounds__(256) void dec_attn_v2(
    const float* __restrict__ pre, const u16* __restrict__ Xproj,
    const u16* __restrict__ Xenc, const float* __restrict__ W2,
    const float* __restrict__ b2, const float* __restrict__ fc_w,
    const float* __restrict__ fc_b, const float* __restrict__ y_prev,
    int step, float* __restrict__ ctx, float* __restrict__ ytil)
{
    const int b = blockIdx.x, tid = threadIdx.x;
    const int lane = tid & 63, w = tid >> 6;
    const int half = tid >> 7, hl = tid & 127;
    const int e8 = hl * 8;
    __shared__ float redw[T_][2];
    __shared__ float ctxs[128][8];
    __shared__ float red[2];

    float pr[8], w2r[8];
    *(float4*)(pr)      = *(const float4*)(pre + (size_t)b * 1024 + e8);
    *(float4*)(pr + 4)  = *(const float4*)(pre + (size_t)b * 1024 + e8 + 4);
    *(float4*)(w2r)     = *(const float4*)(W2 + e8);
    *(float4*)(w2r + 4) = *(const float4*)(W2 + e8 + 4);

    const u16* xp = Xproj + (size_t)b * T_ * 1024;
#pragma unroll
    for (int it = 0; it < 16; ++it) {
        const int t = 2 * it + half;
        const us8 xv = *(const us8*)(xp + t * 1024 + e8);
        float s = 0.0f;
#pragma unroll
        for (int k = 0; k < 8; ++k)
            s += tf(pr[k] + bf2f(xv[k])) * w2r[k];
#pragma unroll
        for (int off = 32; off; off >>= 1) s += __shfl_down(s, off);
        if (lane == 0) redw[t][w & 1] = s;
    }
    __syncthreads();

    // redundant per-thread softmax over 32 scores (cheap, no extra barrier)
    float sc[T_];
    float mx = -1e30f;
#pragma unroll
    for (int t = 0; t < T_; ++t) {
        sc[t] = redw[t][0] + redw[t][1] + b2[0];
        mx = fmaxf(mx, sc[t]);
    }
    float ssum = 0.0f;
#pragma unroll
    for (int t = 0; t < T_; ++t) { sc[t] = __expf(sc[t] - mx); ssum += sc[t]; }
    const float inv = 1.0f / ssum;

    const u16* xe = Xenc + (size_t)b * T_ * 1024;
    float cx[8] = {};
#pragma unroll
    for (int it = 0; it < 16; ++it) {
        const int t = 2 * it + half;
        const us8 xv = *(const us8*)(xe + t * 1024 + e8);
        const float bt = sc[t];
#pragma unroll
        for (int k = 0; k < 8; ++k)
            cx[k] = fmaf(bt, bf2f(xv[k]), cx[k]);
    }
    if (half == 1) {
#pragma unroll
        for (int k = 0; k < 8; ++k) ctxs[hl][k] = cx[k];
    }
    __syncthreads();

    float yt = 0.0f;
    if (half == 0) {
        float fw[8];
        *(float4*)(fw)     = *(const float4*)(fc_w + e8);
        *(float4*)(fw + 4) = *(const float4*)(fc_w + e8 + 4);
        float cv[8];
#pragma unroll
        for (int k = 0; k < 8; ++k) {
            cv[k] = (cx[k] + ctxs[hl][k]) * inv;
            yt += cv[k] * fw[k];
        }
        *(float4*)(ctx + (size_t)b * 1024 + e8)     = *(float4*)(cv);
        *(float4*)(ctx + (size_t)b * 1024 + e8 + 4) = *(float4*)(cv + 4);
    }
#pragma unroll
    for (int off = 32; off; off >>= 1) yt += __shfl_down(yt, off);
    if (lane == 0 && w < 2) red[w] = yt;
    __syncthreads();
    if (tid == 0)
        ytil[b] = red[0] + red[1]
                + y_prev[(size_t)b * T_ + step] * fc_w[1024] + fc_b[0];
}

__global__ __launch_bounds__(256) void final_out(
    const float* __restrict__ d, const float* __restrict__ ctx,
    const float* __restrict__ ffw, const float* __restrict__ ffb,
    float* __restrict__ out)
{
    const int b = blockIdx.x, tid = threadIdx.x;
    float s = 0.0f;
#pragma unroll
    for (int q = 0; q < 4; ++q) {
        const int e = tid + 256 * q;
        s += d[(size_t)b * 1024 + e] * ffw[e] + ctx[(size_t)b * 1024 + e] * ffw[1024 + e];
    }
#pragma unroll
    for (int off = 32; off; off >>= 1) s += __shfl_down(s, off);
    __shared__ float red[4];
    if ((tid & 63) == 0) red[tid >> 6] = s;
    __syncthreads();
    if (tid == 0) out[b] = red[0] + red[1] + red[2] + red[3] + ffb[0];
}

// ===========================================================================
// Fallback fp32-VALU path (R3, proven) — unchanged
// ===========================================================================
__global__ __launch_bounds__(256) void attn_prep(
    const float* __restrict__ X, const float* __restrict__ eaw, float* __restrict__ alpha)
{
    const int b = blockIdx.x, tid = threadIdx.x;
    __shared__ float wx[T_];
    __shared__ float red[4];
    if (tid < T_) wx[tid] = eaw[2 * H_ + tid];
    __syncthreads();
    const float* xb = X + (size_t)b * T_ * I_;
    float a0 = 0.0f, a1 = 0.0f;
#pragma unroll
    for (int t = 0; t < T_; ++t) {
        a0 = fmaf(xb[t * I_ + tid], wx[t], a0);
        a1 = fmaf(xb[t * I_ + tid + 256], wx[t], a1);
    }
    float m = fmaxf(a0, a1);
#pragma unroll
    for (int off = 32; off; off >>= 1) m = fmaxf(m, __shfl_down(m, off));
    if ((tid & 63) == 0) red[tid >> 6] = m;
    __syncthreads();
    m = fmaxf(fmaxf(red[0], red[1]), fmaxf(red[2], red[3]));
    __syncthreads();
    const float e0 = expf(a0 - m), e1 = expf(a1 - m);
    float ssum = e0 + e1;
#pragma unroll
    for (int off = 32; off; off >>= 1) ssum += __shfl_down(ssum, off);
    if ((tid & 63) == 0) red[tid >> 6] = ssum;
    __syncthreads();
    const float inv = 1.0f / (red[0] + red[1] + red[2] + red[3]);
    alpha[(size_t)b * I_ + tid]       = e0 * inv;
    alpha[(size_t)b * I_ + tid + 256] = e1 * inv;
}

template <int BM, int BN, int BK, int TM, int TN, typename TA, typename TC>
__global__ __launch_bounds__(256) void gemm(
    int M, int N,
    const TA* __restrict__ A1, int lda1, const float* __restrict__ B1, int ldb1, int K1,
    const TA* __restrict__ A2, int lda2, const float* __restrict__ B2, int ldb2, int K2,
    const float* __restrict__ ascale, int ldsc,
    const float* __restrict__ bias1, const float* __restrict__ bias2,
    const float* __restrict__ u, const float* __restrict__ v,
    TC* __restrict__ C, int ldc)
{
    constexpr int TCOLS = BN / TN;
    constexpr int KCH = BK / 4;
    constexpr int ROWS_PER_PASS = 256 / KCH;

    __shared__ float As[BK][BM + 4];
    __shared__ float Bs[BK][BN + 4];

    const int tid = threadIdx.x;
    const int tn = tid % TCOLS;
    const int tm = tid / TCOLS;
    const int bn = blockIdx.x * BN;
    const int bm = blockIdx.y * BM;
    const int lrow = tid / KCH;
    const int lkc  = (tid % KCH) * 4;

    float acc[TM][TN];
#pragma unroll
    for (int i = 0; i < TM; ++i)
#pragma unroll
        for (int j = 0; j < TN; ++j) acc[i][j] = 0.0f;

    for (int pair = 0; pair < 2; ++pair) {
        const TA* A  = pair ? A2 : A1;
        const float* Bp = pair ? B2 : B1;
        const float* sc = pair ? nullptr : ascale;
        const int lda = pair ? lda2 : lda1;
        const int ldb = pair ? ldb2 : ldb1;
        const int K   = pair ? K2 : K1;
        if (K == 0) continue;
        for (int k0 = 0; k0 < K; k0 += BK) {
            __syncthreads();
#pragma unroll
            for (int r = 0; r < BM; r += ROWS_PER_PASS) {
                const int row = bm + r + lrow;
                float4 val = ld4(A + (size_t)row * lda + (k0 + lkc));
                if (sc) {
                    const float4 s = *(const float4*)(sc + (size_t)row * ldsc + (k0 + lkc));
                    val.x *= s.x; val.y *= s.y; val.z *= s.z; val.w *= s.w;
                }
                As[lkc + 0][r + lrow] = val.x;
                As[lkc + 1][r + lrow] = val.y;
                As[lkc + 2][r + lrow] = val.z;
                As[lkc + 3][r + lrow] = val.w;
            }
#pragma unroll
            for (int r = 0; r < BN; r += ROWS_PER_PASS) {
                const float4 val = *(const float4*)(Bp + (size_t)(bn + r + lrow) * ldb + (k0 + lkc));
                Bs[lkc + 0][r + lrow] = val.x;
                Bs[lkc + 1][r + lrow] = val.y;
                Bs[lkc + 2][r + lrow] = val.z;
                Bs[lkc + 3][r + lrow] = val.w;
            }
            __syncthreads();
#pragma unroll
            for (int k = 0; k < BK; ++k) {
                float a[TM], bv[TN];
#pragma unroll
                for (int i = 0; i < TM; ++i) a[i] = As[k][tm * TM + i];
#pragma unroll
                for (int j = 0; j < TN; ++j) bv[j] = Bs[k][tn * TN + j];
#pragma unroll
                for (int i = 0; i < TM; ++i)
#pragma unroll
                    for (int j = 0; j < TN; ++j)
                        acc[i][j] = fmaf(a[i], bv[j], acc[i][j]);
            }
        }
    }

#pragma unroll
    for (int i = 0; i < TM; ++i) {
        const int m = bm + tm * TM + i;
        const float um = u ? u[m] : 0.0f;
#pragma unroll
        for (int j = 0; j < TN; j += 4) {
            const int n = bn + tn * TN + j;
            float r[4];
#pragma unroll
            for (int q = 0; q < 4; ++q) {
                float val = acc[i][j + q];
                if (bias1) val += bias1[n + q];
                if (bias2) val += bias2[n + q];
                if (u)     val += um * v[n + q];
                r[q] = val;
            }
            if constexpr (sizeof(TC) == 4) {
                float4 f; f.x = r[0]; f.y = r[1]; f.z = r[2]; f.w = r[3];
                *(float4*)((float*)C + (size_t)m * ldc + n) = f;
            } else {
                ushort4 s;
                s.x = f2bf(r[0]); s.y = f2bf(r[1]); s.z = f2bf(r[2]); s.w = f2bf(r[3]);
                *(ushort4*)((u16*)C + (size_t)m * ldc + n) = s;
            }
        }
    }
}

template <typename TX>
__global__ __launch_bounds__(256) void lstm_pw(
    const float* __restrict__ gates, float* __restrict__ h, float* __restrict__ c,
    TX* __restrict__ xenc, int t)
{
    const size_t idx = (size_t)blockIdx.x * 256 + threadIdx.x;
    const int b = (int)(idx >> 10);
    const int j = (int)(idx & 1023);
    const float* g = gates + ((size_t)b << 12);
    const float gi = g[j], gf = g[j + 1024], gg = g[j + 2048], go = g[j + 3072];
    const float si = 1.0f / (1.0f + expf(-gi));
    const float sf = 1.0f / (1.0f + expf(-gf));
    const float so = 1.0f / (1.0f + expf(-go));
    const float cn = sf * c[idx] + si * tanhf(gg);
    const float hn = so * tanhf(cn);
    c[idx] = cn;
    h[idx] = hn;
    if (xenc) {
        if constexpr (sizeof(TX) == 4) ((float*)xenc)[(((size_t)b * T_ + t) << 10) + j] = hn;
        else ((u16*)xenc)[(((size_t)b * T_ + t) << 10) + j] = f2bf(hn);
    }
}

template <typename TX>
__global__ __launch_bounds__(256) void dec_attn(
    const float* __restrict__ pre, const TX* __restrict__ Xproj,
    const TX* __restrict__ Xenc, const float* __restrict__ W2,
    const float* __restrict__ b2, const float* __restrict__ fc_w,
    const float* __restrict__ fc_b, const float* __restrict__ y_prev,
    int step, float* __restrict__ ctx, float* __restrict__ ytil)
{
    const int b = blockIdx.x, tid = threadIdx.x;
    __shared__ float red[4];
    __shared__ float sc[T_];
    float pr[4], w2r[4];
#pragma unroll
    for (int q = 0; q < 4; ++q) {
        pr[q]  = pre[(size_t)b * 1024 + tid + 256 * q];
        w2r[q] = W2[tid + 256 * q];
    }
    const TX* xp = Xproj + (size_t)b * T_ * 1024;
    for (int t = 0; t < T_; ++t) {
        float s = 0.0f;
#pragma unroll
        for (int q = 0; q < 4; ++q)
            s += tanhf(pr[q] + ld1(xp + t * 1024 + tid + 256 * q)) * w2r[q];
#pragma unroll
        for (int off = 32; off; off >>= 1) s += __shfl_down(s, off);
        if ((tid & 63) == 0) red[tid >> 6] = s;
        __syncthreads();
        if (tid == 0) sc[t] = red[0] + red[1] + red[2] + red[3] + b2[0];
        __syncthreads();
    }
    float mx = -1e30f;
#pragma unroll
    for (int t = 0; t < T_; ++t) mx = fmaxf(mx, sc[t]);
    float beta[T_];
    float ssum = 0.0f;
#pragma unroll
    for (int t = 0; t < T_; ++t) { beta[t] = expf(sc[t] - mx); ssum += beta[t]; }
    const float inv = 1.0f / ssum;
    const TX* xe = Xenc + (size_t)b * T_ * 1024;
    float cx[4] = {0.0f, 0.0f, 0.0f, 0.0f};
    for (int t = 0; t < T_; ++t) {
        const float bt = beta[t];
#pragma unroll
        for (int q = 0; q < 4; ++q)
            cx[q] = fmaf(bt, ld1(xe + t * 1024 + tid + 256 * q), cx[q]);
    }
    float yt = 0.0f;
#pragma unroll
    for (int q = 0; q < 4; ++q) {
        const float cv = cx[q] * inv;
        ctx[(size_t)b * 1024 + tid + 256 * q] = cv;
        yt += cv * fc_w[tid + 256 * q];
    }
#pragma unroll
    for (int off = 32; off; off >>= 1) yt += __shfl_down(yt, off);
    if ((tid & 63) == 0) red[tid >> 6] = yt;
    __syncthreads();
    if (tid == 0)
        ytil[b] = red[0] + red[1] + red[2] + red[3]
                + y_prev[(size_t)b * T_ + step] * fc_w[1024] + fc_b[0];
}

// ===========================================================================
static void run_mfma(void* const* d_in, float* out, char* ws, hipStream_t stream)
{
    const float* X      = (const float*)d_in[0];
    const float* y_prev = (const float*)d_in[1];
    const float* eaw    = (const float*)d_in[2];
    const float* Wih_e  = (const float*)d_in[4];
    const float* Whh_e  = (const float*)d_in[5];
    const float* bih_e  = (const float*)d_in[6];
    const float* bhh_e  = (const float*)d_in[7];
    const float* W1     = (const float*)d_in[8];
    const float* b1     = (const float*)d_in[9];
    const float* W2     = (const float*)d_in[10];
    const float* b2     = (const float*)d_in[11];
    const float* Wih_d  = (const float*)d_in[12];
    const float* Whh_d  = (const float*)d_in[13];
    const float* bih_d  = (const float*)d_in[14];
    const float* bhh_d  = (const float*)d_in[15];
    const float* fc_w   = (const float*)d_in[16];
    const float* fc_b   = (const float*)d_in[17];
    const float* ff_w   = (const float*)d_in[18];
    const float* ff_b   = (const float*)d_in[19];

    auto au = [](size_t x) { return (x + 255) & ~(size_t)255; };
    char* p = ws;
    u16* Xenc   = (u16*)p;    p += au((size_t)B_ * T_ * H_ * 2);   // 134 MB
    u16* Xt     = (u16*)p;                                         // union:
    u16* Xproj  = (u16*)p;    p += au((size_t)B_ * T_ * H_ * 2);   // 134 MB
    float* h    = (float*)p;  p += au((size_t)B_ * H_ * 4);        // decoder d
    float* c    = (float*)p;  p += au((size_t)B_ * H_ * 4);
    u16* hbf0   = (u16*)p;    p += au((size_t)B_ * H_ * 2);
    u16* hbf1   = (u16*)p;    p += au((size_t)B_ * H_ * 2);
    u16* c_bf   = (u16*)p;    p += au((size_t)B_ * H_ * 2);
    float* pre  = (float*)p;  p += au((size_t)B_ * E_ * 4);
    float* ctx  = (float*)p;  p += au((size_t)B_ * E_ * 4);
    u16* Wih_e_p = (u16*)p;   p += au((size_t)G_ * I_ * 2);
    u16* Whh_e_p = (u16*)p;   p += au((size_t)G_ * H_ * 2);
    u16* Whh_d_p = (u16*)p;   p += au((size_t)G_ * H_ * 2);
    u16* W1dc_bf = (u16*)p;   p += au((size_t)E_ * 2048 * 2);
    u16* W1x_bf  = (u16*)p;   p += au((size_t)E_ * 1024 * 2);
    float* bias_e_p = (float*)p; p += au((size_t)G_ * 4);
    float* bias_d_p = (float*)p; p += au((size_t)G_ * 4);
    float* wv_p     = (float*)p; p += au((size_t)G_ * 4);
    float* ytil     = (float*)p;

    // weight prep (permuted gates layout)
    perm_w<<<(G_ * (I_ / 4)) / 256, 256, 0, stream>>>(Wih_e, Wih_e_p, I_);
    perm_w<<<(G_ * (H_ / 4)) / 256, 256, 0, stream>>>(Whh_e, Whh_e_p, H_);
    perm_w<<<(G_ * (H_ / 4)) / 256, 256, 0, stream>>>(Whh_d, Whh_d_p, H_);
    perm_bv<<<G_ / 256, 256, 0, stream>>>(bih_e, bhh_e, nullptr, bias_e_p, nullptr);
    perm_bv<<<G_ / 256, 256, 0, stream>>>(bih_d, bhh_d, Wih_d, bias_d_p, wv_p);
    split_w1<<<(E_ * 768) / 256, 256, 0, stream>>>(W1, W1dc_bf, W1x_bf);

    hipMemsetAsync(c, 0, (size_t)B_ * H_ * 4, stream);          // encoder c=0
    attn_prep_xt<<<B_, 256, 0, stream>>>(X, eaw, Xt);

    // ---- encoder: fused gates-GEMM + LSTM (h_bf double-buffered)
    // t=0: h=0 -> skip recurrent pair (K2=0); hbf0 never read.
    for (int t = 0; t < T_; ++t) {
        u16* hin  = (t & 1) ? hbf1 : hbf0;
        u16* hout = (t & 1) ? hbf0 : hbf1;
        gemm_lstm<true><<<dim3(H_ / 16, B_ / 256), 256, 0, stream>>>(
            Xt + (size_t)t * B_ * I_, I_, Wih_e_p, I_,
            hin, H_, Whh_e_p, t == 0 ? 0 : H_,
            bias_e_p, nullptr, nullptr,
            c, nullptr, hout, nullptr, Xenc, t);
    }

    // ---- Xproj = Xenc @ W1x^T + b1 (overwrites Xt union; Xt dead)
    gemm_bf16<128, 128, u16><<<dim3(E_ / 128, (B_ * T_) / 128), 256, 0, stream>>>(
        Xenc, H_, W1x_bf, H_, H_,
        nullptr, 0, nullptr, 0, 0,
        b1, nullptr, nullptr, nullptr, Xproj, E_);

    // ---- decoder
    hipMemsetAsync(c, 0, (size_t)B_ * H_ * 4, stream);          // decoder c=0
    hipMemsetAsync(pre, 0, (size_t)B_ * E_ * 4, stream);        // pre(0)=0 (d=c=0)

    for (int t = 0; t < T_; ++t) {
        u16* hin  = (t & 1) ? hbf1 : hbf0;
        u16* hout = (t & 1) ? hbf0 : hbf1;
        // pre = d @ W1[:, :1024]^T + c @ W1[:, 1024:2048]^T  (64x64 tile:
        // 512 blocks -> ~4/CU; t=0 skipped, memset above stands)
        if (t > 0)
            gemm_bf16<64, 64, float><<<dim3(E_ / 64, B_ / 64), 256, 0, stream>>>(
                hin, H_, W1dc_bf, 2048, H_,
                c_bf, H_, W1dc_bf + 1024, 2048, H_,
                nullptr, nullptr, nullptr, nullptr, pre, E_);
        dec_attn_v2<<<B_, 256, 0, stream>>>(pre, Xproj, Xenc, W2, b2, fc_w, fc_b,
                                            y_prev, t, ctx, ytil);
        // gates = d @ Whh_d^T + bias + ytil[m]*wv[n]; t=0: d=0 -> K1=0
        gemm_lstm<false><<<dim3(H_ / 16, B_ / 256), 256, 0, stream>>>(
            hin, H_, Whh_d_p, t == 0 ? 0 : H_,
            (const u16*)nullptr, 0, nullptr, 0,
            bias_d_p, ytil, wv_p,
            c, t == T_ - 1 ? h : nullptr, hout, c_bf, nullptr, t);
    }

    final_out<<<B_, 256, 0, stream>>>(h, ctx, ff_w, ff_b, out);
}

// ---- R3 lean fallback ------------------------------------------------------
static void run_fallback(void* const* d_in, float* out, char* ws, hipStream_t stream)
{
    const float* X      = (const float*)d_in[0];
    const float* y_prev = (const float*)d_in[1];
    const float* eaw    = (const float*)d_in[2];
    const float* Wih_e  = (const float*)d_in[4];
    const float* Whh_e  = (const float*)d_in[5];
    const float* bih_e  = (const float*)d_in[6];
    const float* bhh_e  = (const float*)d_in[7];
    const float* W1     = (const float*)d_in[8];
    const float* b1     = (const float*)d_in[9];
    const float* W2     = (const float*)d_in[10];
    const float* b2     = (const float*)d_in[11];
    const float* Wih_d  = (const float*)d_in[12];
    const float* Whh_d  = (const float*)d_in[13];
    const float* bih_d  = (const float*)d_in[14];
    const float* bhh_d  = (const float*)d_in[15];
    const float* fc_w   = (const float*)d_in[16];
    const float* fc_b   = (const float*)d_in[17];
    const float* ff_w   = (const float*)d_in[18];
    const float* ff_b   = (const float*)d_in[19];

    auto au = [](size_t x) { return (x + 255) & ~(size_t)255; };
    char* p = ws;
    float* alpha = (float*)p;  p += au((size_t)B_ * I_ * 4);
    u16*   Xenc  = (u16*)p;    p += au((size_t)B_ * T_ * H_ * 2);
    u16*   Xproj = (u16*)p;    p += au((size_t)B_ * T_ * H_ * 2);
    float* gates = (float*)p;  p += au((size_t)B_ * G_ * 4);
    float* h     = (float*)p;  p += au((size_t)B_ * H_ * 4);
    float* c     = (float*)p;  p += au((size_t)B_ * H_ * 4);
    float* pre   = (float*)p;  p += au((size_t)B_ * E_ * 4);
    float* ctx   = (float*)p;  p += au((size_t)B_ * E_ * 4);
    float* ytil  = (float*)p;

    hipMemsetAsync(h, 0, (size_t)B_ * H_ * 4, stream);
    hipMemsetAsync(c, 0, (size_t)B_ * H_ * 4, stream);

    attn_prep<<<B_, 256, 0, stream>>>(X, eaw, alpha);

    for (int t = 0; t < T_; ++t) {
        gemm<128, 128, 16, 8, 8, float, float><<<dim3(G_ / 128, B_ / 128), 256, 0, stream>>>(
            B_, G_,
            X + (size_t)t * I_, T_ * I_, Wih_e, I_, I_,
            h, H_, Whh_e, H_, H_,
            alpha, I_,
            bih_e, bhh_e, nullptr, nullptr, gates, G_);
        lstm_pw<u16><<<(B_ * H_) / 256, 256, 0, stream>>>(gates, h, c, Xenc, t);
    }

    gemm<128, 128, 16, 8, 8, u16, u16><<<dim3(E_ / 128, (B_ * T_) / 128), 256, 0, stream>>>(
        B_ * T_, E_,
        Xenc, H_, W1 + 2048, 3072, H_,
        (const u16*)nullptr, 0, nullptr, 0, 0,
        nullptr, 0,
        b1, nullptr, nullptr, nullptr, Xproj, E_);

    hipMemsetAsync(h, 0, (size_t)B_ * H_ * 4, stream);
    hipMemsetAsync(c, 0, (size_t)B_ * H_ * 4, stream);

    for (int t = 0; t < T_; ++t) {
        gemm<64, 64, 16, 4, 4, float, float><<<dim3(E_ / 64, B_ / 64), 256, 0, stream>>>(
            B_, E_,
            h, H_, W1, 3072, H_,
            c, H_, W1 + 1024, 3072, H_,
            nullptr, 0,
            nullptr, nullptr, nullptr, nullptr, pre, E_);
        dec_attn<u16><<<B_, 256, 0, stream>>>(pre, Xproj, Xenc, W2, b2, fc_w, fc_b,
                                              y_prev, t, ctx, ytil);
        gemm<128, 128, 16, 8, 8, float, float><<<dim3(G_ / 128, B_ / 128), 256, 0, stream>>>(
            B_, G_,
            h, H_, Whh_d, H_, H_,
            (const float*)nullptr, 0, nullptr, 0, 0,
            nullptr, 0,
            bih_d, bhh_d, ytil, Wih_d, gates, G_);
        lstm_pw<float><<<(B_ * H_) / 256, 256, 0, stream>>>(gates, h, c, nullptr, t);
    }

    final_out<<<B_, 256, 0, stream>>>(h, ctx, ff_w, ff_b, out);
}

extern "C" void kernel_launch(void* const* d_in, const int* in_sizes, int n_in,
                              void* d_out, int out_size, void* d_ws, size_t ws_size,
                              hipStream_t stream)
{
    auto au = [](size_t x) { return (x + 255) & ~(size_t)255; };
    const size_t needM =
        2 * au((size_t)B_ * T_ * H_ * 2) +           // Xenc + (Xt|Xproj union)
        2 * au((size_t)B_ * H_ * 4) +                // h, c
        3 * au((size_t)B_ * H_ * 2) +                // hbf0, hbf1, c_bf
        2 * au((size_t)B_ * E_ * 4) +                // pre, ctx
        au((size_t)G_ * I_ * 2) + 2 * au((size_t)G_ * H_ * 2) +
        au((size_t)E_ * 2048 * 2) + au((size_t)E_ * 1024 * 2) +
        3 * au((size_t)G_ * 4) +                     // bias_e_p, bias_d_p, wv_p
        au((size_t)B_ * 4) + 4096;                   // ytil + slack

    if (ws_size >= needM)
        run_mfma(d_in, (float*)d_out, (char*)d_ws, stream);
    else
        run_fallback(d_in, (float*)d_out, (char*)d_ws, stream);
}